// Round 6
// baseline (323.770 us; speedup 1.0000x reference)
//
#include <hip/hip_runtime.h>
#include <hip/hip_cooperative_groups.h>
#include <math.h>

#define HID   2048
#define NEXP  64
#define NTOK  16384
#define SBLK  64      // sinkhorn blocks
#define TOLF  1e-4f
#define EPSF  1e-8f

typedef _Float16 f16x8 __attribute__((ext_vector_type(8)));
typedef float    f32x4 __attribute__((ext_vector_type(4)));

// ---------------------------------------------------------------------------
// Kernel 0: split W (64x2048 fp32) into Wh + Wl*2048 (f16, same [e][k] layout).
// f16x3 trick: x@W ~= xh@Wh + (xh@Wl' + xl'@Wh)/2048, residuals exact
// (Sterbenz), net error ~2^-24 * scale -- below fp32 reassociation noise.
// ---------------------------------------------------------------------------
__global__ __launch_bounds__(256) void convert_w(const float* __restrict__ W,
                                                 _Float16* __restrict__ Wh,
                                                 _Float16* __restrict__ Wl) {
    const int i = ((int)blockIdx.x * 256 + (int)threadIdx.x) * 8;
    const float4 w0 = *(const float4*)(W + i);
    const float4 w1 = *(const float4*)(W + i + 4);
    float v[8] = {w0.x, w0.y, w0.z, w0.w, w1.x, w1.y, w1.z, w1.w};
    f16x8 h, l;
#pragma unroll
    for (int j = 0; j < 8; ++j) {
        const _Float16 hh = (_Float16)v[j];
        h[j] = hh;
        l[j] = (_Float16)((v[j] - (float)hh) * 2048.0f);
    }
    *(f16x8*)(Wh + i) = h;
    *(f16x8*)(Wl + i) = l;
}

// ---------------------------------------------------------------------------
// Kernel 1: f16x3 MFMA logits, B staged through LDS.
// R6 change: 1024-thr/1-block-per-CU -> 512-thr/2-blocks-per-CU.
// R5 post-mortem: gemm ~69us vs ~22us A-stream floor; 2-barrier-per-chunk
// lockstep with NO co-resident block = CU idles in every drain (m114: TLP
// between blocks is what absorbs barrier stalls). Block = 8 waves
// (2 token-groups x 4 k-slices), 32 tokens, grid = 512, LDS 40KB -> 2
// blocks/CU (80/160KB), same 16 waves/CU, barrier phases interleave.
// Staging: thread loads one full 64B row-chunk (coalesced); MFMA schedule,
// chunk order, epilogue reduce order UNCHANGED -> bitwise-identical L.
// ---------------------------------------------------------------------------
#define BSTRIDE 40   // f16 per LDS B row (32 data + 8 pad, 16B-aligned)

__global__ __launch_bounds__(512, 4) void gemm_mfma(const float* __restrict__ x,
                                                    const _Float16* __restrict__ Wh,
                                                    const _Float16* __restrict__ Wl,
                                                    float* __restrict__ L) {
    // 40 KB static LDS: B chunks (40960 B) during the loop, red[8][1024] f32
    // (32768 B) in the epilogue (aliased; safe after final barrier).
    __shared__ __align__(16) char smem[40960];
    _Float16* Bs  = (_Float16*)smem;   // [(wk*2+a)*64 + row][BSTRIDE]
    float*    red = (float*)smem;      // [wave][n*256 + r*64 + lane]

    const int tid    = (int)threadIdx.x;
    const int waveid = tid >> 6;       // 0..7
    const int wt     = waveid >> 2;    // token group 0..1 (16 tokens each)
    const int wk     = waveid & 3;     // k-slice 0..3 (512 k each)
    const int lane   = tid & 63;
    const int lo     = lane & 15;      // token row (A) / expert col (D)
    const int hi     = lane >> 4;      // k-block 0..3
    const int t0     = (int)blockIdx.x * 32;
    const int kb     = wk * 512;

    // staging: group-local thread gt (0..127) loads one 64B row-chunk
    const int gt   = wt * 64 + lane;   // 0..127 within this wk group
    const int sa   = gt >> 6;          // 0 = Wh, 1 = Wl
    const int srow = gt & 63;          // 0..63
    const _Float16* sgp = (sa ? Wl : Wh) + (size_t)srow * HID + kb;
    const int swbase = ((wk * 2 + sa) * 64 + srow) * BSTRIDE;

    const float* xp = x + (size_t)(t0 + wt * 16 + lo) * HID + kb + hi * 8;

    f32x4 acc_hh[4], acc_hl[4];
#pragma unroll
    for (int n = 0; n < 4; ++n) {
        acc_hh[n] = f32x4{0.f, 0.f, 0.f, 0.f};
        acc_hl[n] = f32x4{0.f, 0.f, 0.f, 0.f};
    }

    // prologue: stage chunk 0 (4 x 16B per thread = 64B contiguous)
    f16x8 s0 = *(const f16x8*)(sgp);
    f16x8 s1 = *(const f16x8*)(sgp + 8);
    f16x8 s2 = *(const f16x8*)(sgp + 16);
    f16x8 s3 = *(const f16x8*)(sgp + 24);
    *(f16x8*)&Bs[swbase]      = s0;
    *(f16x8*)&Bs[swbase + 8]  = s1;
    *(f16x8*)&Bs[swbase + 16] = s2;
    *(f16x8*)&Bs[swbase + 24] = s3;
    __syncthreads();

    // 1-step-ahead A prefetch
    float4 a0n = *(const float4*)(xp);
    float4 a1n = *(const float4*)(xp + 4);

    for (int c = 0; c < 16; ++c) {
        // issue next chunk's B staging loads early (no wait here)
        if (c + 1 < 16) {
            s0 = *(const f16x8*)(sgp + (c + 1) * 32);
            s1 = *(const f16x8*)(sgp + (c + 1) * 32 + 8);
            s2 = *(const f16x8*)(sgp + (c + 1) * 32 + 16);
            s3 = *(const f16x8*)(sgp + (c + 1) * 32 + 24);
        }

        const float4 a0 = a0n, a1 = a1n;
        const int ko = ((c + 1 < 16) ? (c + 1) : 15) * 32;
        a0n = *(const float4*)(xp + ko);
        a1n = *(const float4*)(xp + ko + 4);

        // B fragments from LDS
        f16x8 bh[4], bl[4];
#pragma unroll
        for (int n = 0; n < 4; ++n) {
            bh[n] = *(const f16x8*)&Bs[((wk * 2 + 0) * 64 + lo + n * 16) * BSTRIDE + hi * 8];
            bl[n] = *(const f16x8*)&Bs[((wk * 2 + 1) * 64 + lo + n * 16) * BSTRIDE + hi * 8];
        }

        // split current A chunk: xh (RTN) + xl*2048 (residual exact)
        f16x8 ah, al;
        const float av[8] = {a0.x, a0.y, a0.z, a0.w, a1.x, a1.y, a1.z, a1.w};
#pragma unroll
        for (int j = 0; j < 8; ++j) {
            const _Float16 hh = (_Float16)av[j];
            ah[j] = hh;
            al[j] = (_Float16)((av[j] - (float)hh) * 2048.0f);
        }

        // 12 MFMA; dependent acc_hl pairs separated by independent MFMAs
#pragma unroll
        for (int n = 0; n < 4; ++n)
            acc_hh[n] = __builtin_amdgcn_mfma_f32_16x16x32_f16(ah, bh[n], acc_hh[n], 0, 0, 0);
#pragma unroll
        for (int n = 0; n < 4; ++n)
            acc_hl[n] = __builtin_amdgcn_mfma_f32_16x16x32_f16(ah, bl[n], acc_hl[n], 0, 0, 0);
#pragma unroll
        for (int n = 0; n < 4; ++n)
            acc_hl[n] = __builtin_amdgcn_mfma_f32_16x16x32_f16(al, bh[n], acc_hl[n], 0, 0, 0);

        __syncthreads();                 // all waves done reading chunk c
        if (c + 1 < 16) {
            *(f16x8*)&Bs[swbase]      = s0;   // write chunk c+1
            *(f16x8*)&Bs[swbase + 8]  = s1;
            *(f16x8*)&Bs[swbase + 16] = s2;
            *(f16x8*)&Bs[swbase + 24] = s3;
            __syncthreads();
        }
    }

    // epilogue: per-wave partials -> red (aliases Bs; all B reads barriered)
#pragma unroll
    for (int n = 0; n < 4; ++n)
#pragma unroll
        for (int r = 0; r < 4; ++r)
            red[waveid * 1024 + n * 256 + r * 64 + lane] =
                acc_hh[n][r] + acc_hl[n][r] * (1.0f / 2048.0f);
    __syncthreads();

    // cross-wk reduce + coalesced write. Thread tid owns outputs o=tid*4..+3:
    // t_loc = o>>6 (0..31), e = o&63. wt_src = t_loc>>4, tl = t_loc&15.
    // Source idx: (e>>4)*256 + (tl&3)*64 + (tl>>2)*16 + (e&15).
    {
        const int o      = tid * 4;
        const int t_loc  = o >> 6;
        const int e      = o & 63;
        const int wt_src = t_loc >> 4;
        const int tl     = t_loc & 15;
        const int idx    = (e >> 4) * 256 + (tl & 3) * 64 + (tl >> 2) * 16 + (e & 15);
        float4 s = *(const float4*)&red[(wt_src * 4 + 0) * 1024 + idx];
#pragma unroll
        for (int q = 1; q < 4; ++q) {
            const float4 v = *(const float4*)&red[(wt_src * 4 + q) * 1024 + idx];
            s.x += v.x; s.y += v.y; s.z += v.z; s.w += v.w;
        }
        *(float4*)(L + (size_t)(t0 + t_loc) * NEXP + e) = s;
    }
}

// ---------------------------------------------------------------------------
// wave-wide f32 sum via DPP (VALU-only). Kept from R5 (neutral but strictly
// fewer LDS ops). row_shr 1/2/4/8 within 16-lane rows, row_bcast15/31 merge
// rows; lane 63 holds the total; readlane -> wave-uniform.
// ---------------------------------------------------------------------------
__device__ __forceinline__ float wave_sum64(float v) {
    int x;
    float t;
    x = __builtin_bit_cast(int, v);
    t = __builtin_bit_cast(float, __builtin_amdgcn_update_dpp(0, x, 0x111, 0xf, 0xf, true)); v += t;
    x = __builtin_bit_cast(int, v);
    t = __builtin_bit_cast(float, __builtin_amdgcn_update_dpp(0, x, 0x112, 0xf, 0xf, true)); v += t;
    x = __builtin_bit_cast(int, v);
    t = __builtin_bit_cast(float, __builtin_amdgcn_update_dpp(0, x, 0x114, 0xf, 0xf, true)); v += t;
    x = __builtin_bit_cast(int, v);
    t = __builtin_bit_cast(float, __builtin_amdgcn_update_dpp(0, x, 0x118, 0xf, 0xf, true)); v += t;
    x = __builtin_bit_cast(int, v);
    t = __builtin_bit_cast(float, __builtin_amdgcn_update_dpp(0, x, 0x142, 0xa, 0xf, true)); v += t;
    x = __builtin_bit_cast(int, v);
    t = __builtin_bit_cast(float, __builtin_amdgcn_update_dpp(0, x, 0x143, 0xc, 0xf, true)); v += t;
    return __builtin_bit_cast(float, __builtin_amdgcn_readlane(__builtin_bit_cast(int, v), 63));
}

// ---------------------------------------------------------------------------
// Kernel 2 (cooperative): sinkhorn + top-2 + softmax gather. UNCHANGED from
// R5 (isolating the gemm change). Grid = 64 blocks x 1024 threads.
// ---------------------------------------------------------------------------
__global__ __launch_bounds__(1024) void sinkhorn_router(const float* __restrict__ L,
                                                        float* __restrict__ colbuf,
                                                        float* __restrict__ out,
                                                        int nh) {
    cooperative_groups::grid_group grid = cooperative_groups::this_grid();

    __shared__ float part[16][64];
    __shared__ float redq[64][17];
    __shared__ float d1s[64];
    __shared__ float err_s;

    const int b     = blockIdx.x;   // 0..63
    const int tid   = (int)threadIdx.x;
    const int w     = tid >> 6;     // wave 0..15
    const int lane  = tid & 63;     // expert index
    const int tbase = b * 256 + w * 16;

    float logit[16], cost[16], dreg[16];
#pragma unroll
    for (int j = 0; j < 16; ++j) {
        const int t = tbase + j;
        float l = L[(size_t)t * NEXP + lane];
        for (int h = 1; h < nh; ++h)
            l += L[(size_t)h * NTOK * NEXP + (size_t)t * NEXP + lane];
        logit[j] = l;
        cost[j]  = expf(l);
        dreg[j]  = 0.0f;
    }

    float d1l   = 1.0f;   // this lane's d1[e]
    float d1old = 1.0f;   // previous d1 (used by tid<64 for err)
    int   g     = 0;

    for (;;) {
        // ---- phase A: d0 per token (DPP reduce) + per-wave column partials
        float colacc = 0.0f;
#pragma unroll
        for (int j = 0; j < 16; ++j) {
            const float s = wave_sum64(d1l * cost[j]);   // wave-uniform
            const float d0 = (1.0f / 16384.0f) / (s + EPSF);
            dreg[j] = d0;
            colacc = fmaf(d0, cost[j], colacc);
        }
        part[w][lane] = colacc;
        __syncthreads();

        float* cb = colbuf + (size_t)(g & 1) * (NEXP * SBLK);
        if (tid < 64) {
            float s = part[0][tid];
#pragma unroll
            for (int q = 1; q < 16; ++q) s += part[q][tid];
            cb[tid * SBLK + b] = s;     // reader-coalesced layout [e][b]
        }
        grid.sync();

        // ---- phase B: cross-block column reduction, all 1024 threads ----
        {
            const int e = tid >> 4;     // 0..63
            const int q = tid & 15;     // 0..15 -> blocks q*4..q*4+3
            const float4 v = *(const float4*)(cb + e * SBLK + q * 4);
            redq[e][q] = (v.x + v.y) + (v.z + v.w);
        }
        __syncthreads();

        if (tid < 64) {
            float tot = redq[tid][0];
#pragma unroll
            for (int q = 1; q < 16; ++q) tot += redq[tid][q];
            const float d1n = (1.0f / 64.0f) / (tot + EPSF);
            float diff = fabsf(d1old - d1n);
#pragma unroll
            for (int m = 32; m; m >>= 1) diff += __shfl_xor(diff, m, 64);
            d1s[tid] = d1n;
            d1old    = d1n;
            if (tid == 0) err_s = diff * (1.0f / 64.0f);
        }
        __syncthreads();
        d1l = d1s[lane];
        const float err = err_s;
        ++g;
        if (!(err > TOLF) || g >= 512) break;   // matches while(err>tol); NaN stops
    }

    // ---- final: per token top-2 of d1*cost*d0, softmax gather ----
#pragma unroll 1
    for (int j = 0; j < 16; ++j) {
        const int t = tbase + j;
        const float v = (d1l * cost[j]) * dreg[j];

        float bv = v; int bi = lane;
#pragma unroll
        for (int m = 32; m; m >>= 1) {
            const float ov = __shfl_xor(bv, m, 64);
            const int   oi = __shfl_xor(bi, m, 64);
            if (ov > bv || (ov == bv && oi < bi)) { bv = ov; bi = oi; }
        }
        const int i1 = bi;

        const float v2 = (lane == i1) ? -INFINITY : v;
        float bv2 = v2; int bi2 = lane;
#pragma unroll
        for (int m = 32; m; m >>= 1) {
            const float ov = __shfl_xor(bv2, m, 64);
            const int   oi = __shfl_xor(bi2, m, 64);
            if (ov > bv2 || (ov == bv2 && oi < bi2)) { bv2 = ov; bi2 = oi; }
        }
        const int i2 = bi2;

        float mx = logit[j];
#pragma unroll
        for (int m = 32; m; m >>= 1) mx = fmaxf(mx, __shfl_xor(mx, m, 64));
        const float e = expf(logit[j] - mx);
        float se = e;
#pragma unroll
        for (int m = 32; m; m >>= 1) se += __shfl_xor(se, m, 64);

        const float p1 = __shfl(e, i1, 64) / se;
        const float p2 = __shfl(e, i2, 64) / se;

        if (lane == 0) {
            out[(size_t)t * 2 + 0] = p1;
            out[(size_t)t * 2 + 1] = p2;
            out[(size_t)NTOK * 2 + (size_t)t * 2 + 0] = (float)i1;
            out[(size_t)NTOK * 2 + (size_t)t * 2 + 1] = (float)i2;
        }
    }
}

// ---------------------------------------------------------------------------
// ws layout (4.78 MB total, well under the proven-available 8.4 MB minimum):
//   [0,       256KB)  Wh f16 [64][2048]
//   [256KB,   512KB)  Wl f16 [64][2048] (pre-scaled x2048)
//   [512KB,   4.5MB)  L  f32 [16384][64]
//   [4.5MB,  +32KB )  colbuf (2 x 64 x 64 f32, sinkhorn ping-pong)
// ---------------------------------------------------------------------------
extern "C" void kernel_launch(void* const* d_in, const int* in_sizes, int n_in,
                              void* d_out, int out_size, void* d_ws, size_t ws_size,
                              hipStream_t stream) {
    const float* x = (const float*)d_in[0];
    const float* W = (const float*)d_in[1];
    float* out = (float*)d_out;

    _Float16* Wh = (_Float16*)d_ws;
    _Float16* Wl = Wh + (size_t)NEXP * HID;                  // +131072 elems
    float* L      = (float*)((char*)d_ws + 524288);
    float* colbuf = L + (size_t)NTOK * NEXP;

    convert_w<<<dim3(64), dim3(256), 0, stream>>>(W, Wh, Wl);
    gemm_mfma<<<dim3(512), dim3(512), 0, stream>>>(x, Wh, Wl, L);

    int nh = 1;
    void* args[] = { (void*)&L, (void*)&colbuf, (void*)&out, (void*)&nh };
    hipLaunchCooperativeKernel((void*)sinkhorn_router, dim3(SBLK), dim3(1024),
                               args, 0, stream);
}

// Round 7
// 282.990 us; speedup vs baseline: 1.1441x; 1.1441x over previous
//
#include <hip/hip_runtime.h>
#include <hip/hip_cooperative_groups.h>
#include <math.h>

#define HID   2048
#define NEXP  64
#define NTOK  16384
#define SBLK  64      // sinkhorn blocks
#define TOLF  1e-4f
#define EPSF  1e-8f

typedef _Float16 f16x8 __attribute__((ext_vector_type(8)));
typedef float    f32x4 __attribute__((ext_vector_type(4)));

// ---------------------------------------------------------------------------
// Kernel 0: split W (64x2048 fp32) into Wh + Wl*2048 (f16, same [e][k] layout).
// Also zeroes the sinkhorn barrier counter (fresh per launch; the dispatch
// boundary is the release that makes it visible to sinkhorn_router).
// ---------------------------------------------------------------------------
__global__ __launch_bounds__(256) void convert_w(const float* __restrict__ W,
                                                 _Float16* __restrict__ Wh,
                                                 _Float16* __restrict__ Wl,
                                                 int* __restrict__ cnt) {
    if (blockIdx.x == 0 && threadIdx.x == 0) *cnt = 0;
    const int i = ((int)blockIdx.x * 256 + (int)threadIdx.x) * 8;
    const float4 w0 = *(const float4*)(W + i);
    const float4 w1 = *(const float4*)(W + i + 4);
    float v[8] = {w0.x, w0.y, w0.z, w0.w, w1.x, w1.y, w1.z, w1.w};
    f16x8 h, l;
#pragma unroll
    for (int j = 0; j < 8; ++j) {
        const _Float16 hh = (_Float16)v[j];
        h[j] = hh;
        l[j] = (_Float16)((v[j] - (float)hh) * 2048.0f);
    }
    *(f16x8*)(Wh + i) = h;
    *(f16x8*)(Wl + i) = l;
}

// ---------------------------------------------------------------------------
// Kernel 1: f16x3 MFMA logits, B staged through LDS. EXACT R4 kernel
// (measured ~69us). R6's 512-thr/2-blocks-per-CU split REGRESSED to 97us
// (no cross-block overlap materialized; LDS bank conflicts 2.3M) -> reverted.
// Grid = 256 x 1024 thr (16 waves = 4 token-groups x 4 k-slices).
// ---------------------------------------------------------------------------
#define BSTRIDE 40   // f16 per LDS B row (32 data + 8 pad, 16B-aligned)

__global__ __launch_bounds__(1024, 4) void gemm_mfma(const float* __restrict__ x,
                                                     const _Float16* __restrict__ Wh,
                                                     const _Float16* __restrict__ Wl,
                                                     float* __restrict__ L) {
    __shared__ __align__(16) char smem[65536];
    _Float16* Bs  = (_Float16*)smem;   // [(wk*2+a)*64 + row][BSTRIDE]
    float*    red = (float*)smem;      // [wave][n*256 + r*64 + lane]

    const int tid    = (int)threadIdx.x;
    const int waveid = tid >> 6;       // 0..15
    const int wt     = waveid >> 2;    // token group 0..3 (16 tokens each)
    const int wk     = waveid & 3;     // k-slice 0..3 (512 k each)
    const int lane   = tid & 63;
    const int lo     = lane & 15;      // token row (A) / expert col (D)
    const int hi     = lane >> 4;      // k-block 0..3
    const int t0     = (int)blockIdx.x * 64;
    const int kb     = wk * 512;

    const int gt    = wt * 64 + lane;  // group-local tid
    const int sa    = gt >> 7;         // 0 = Wh, 1 = Wl
    const int srow  = (gt & 127) >> 1; // 0..63
    const int shalf = (gt & 1) * 16;   // 0 or 16 (f16)
    const _Float16* sgp = (sa ? Wl : Wh) + (size_t)srow * HID + kb + shalf;
    const int swbase = ((wk * 2 + sa) * 64 + srow) * BSTRIDE + shalf;

    const float* xp = x + (size_t)(t0 + wt * 16 + lo) * HID + kb + hi * 8;

    f32x4 acc_hh[4], acc_hl[4];
#pragma unroll
    for (int n = 0; n < 4; ++n) {
        acc_hh[n] = f32x4{0.f, 0.f, 0.f, 0.f};
        acc_hl[n] = f32x4{0.f, 0.f, 0.f, 0.f};
    }

    f16x8 sr0 = *(const f16x8*)(sgp);
    f16x8 sr1 = *(const f16x8*)(sgp + 8);
    *(f16x8*)&Bs[swbase]     = sr0;
    *(f16x8*)&Bs[swbase + 8] = sr1;
    __syncthreads();

    float4 a0n = *(const float4*)(xp);
    float4 a1n = *(const float4*)(xp + 4);

    for (int c = 0; c < 16; ++c) {
        if (c + 1 < 16) {
            sr0 = *(const f16x8*)(sgp + (c + 1) * 32);
            sr1 = *(const f16x8*)(sgp + (c + 1) * 32 + 8);
        }

        const float4 a0 = a0n, a1 = a1n;
        const int ko = ((c + 1 < 16) ? (c + 1) : 15) * 32;
        a0n = *(const float4*)(xp + ko);
        a1n = *(const float4*)(xp + ko + 4);

        f16x8 bh[4], bl[4];
#pragma unroll
        for (int n = 0; n < 4; ++n) {
            bh[n] = *(const f16x8*)&Bs[((wk * 2 + 0) * 64 + lo + n * 16) * BSTRIDE + hi * 8];
            bl[n] = *(const f16x8*)&Bs[((wk * 2 + 1) * 64 + lo + n * 16) * BSTRIDE + hi * 8];
        }

        f16x8 ah, al;
        const float av[8] = {a0.x, a0.y, a0.z, a0.w, a1.x, a1.y, a1.z, a1.w};
#pragma unroll
        for (int j = 0; j < 8; ++j) {
            const _Float16 hh = (_Float16)av[j];
            ah[j] = hh;
            al[j] = (_Float16)((av[j] - (float)hh) * 2048.0f);
        }

#pragma unroll
        for (int n = 0; n < 4; ++n)
            acc_hh[n] = __builtin_amdgcn_mfma_f32_16x16x32_f16(ah, bh[n], acc_hh[n], 0, 0, 0);
#pragma unroll
        for (int n = 0; n < 4; ++n)
            acc_hl[n] = __builtin_amdgcn_mfma_f32_16x16x32_f16(ah, bl[n], acc_hl[n], 0, 0, 0);
#pragma unroll
        for (int n = 0; n < 4; ++n)
            acc_hl[n] = __builtin_amdgcn_mfma_f32_16x16x32_f16(al, bh[n], acc_hl[n], 0, 0, 0);

        __syncthreads();
        if (c + 1 < 16) {
            *(f16x8*)&Bs[swbase]     = sr0;
            *(f16x8*)&Bs[swbase + 8] = sr1;
            __syncthreads();
        }
    }

#pragma unroll
    for (int n = 0; n < 4; ++n)
#pragma unroll
        for (int r = 0; r < 4; ++r)
            red[waveid * 1024 + n * 256 + r * 64 + lane] =
                acc_hh[n][r] + acc_hl[n][r] * (1.0f / 2048.0f);
    __syncthreads();

    {
        const int o      = tid * 4;
        const int t_loc  = o >> 6;
        const int e      = o & 63;
        const int wt_src = t_loc >> 4;
        const int tl     = t_loc & 15;
        const int idx    = (e >> 4) * 256 + (tl & 3) * 64 + (tl >> 2) * 16 + (e & 15);
        float4 s = *(const float4*)&red[(wt_src * 4 + 0) * 1024 + idx];
#pragma unroll
        for (int q = 1; q < 4; ++q) {
            const float4 v = *(const float4*)&red[(wt_src * 4 + q) * 1024 + idx];
            s.x += v.x; s.y += v.y; s.z += v.z; s.w += v.w;
        }
        *(float4*)(L + (size_t)(t0 + t_loc) * NEXP + e) = s;
    }
}

// ---------------------------------------------------------------------------
// wave-wide f32 sum via DPP (VALU-only). row_shr 1/2/4/8 within 16-lane rows,
// row_bcast15/31 merge rows; lane 63 holds total; readlane -> wave-uniform.
// ---------------------------------------------------------------------------
__device__ __forceinline__ float wave_sum64(float v) {
    int x;
    float t;
    x = __builtin_bit_cast(int, v);
    t = __builtin_bit_cast(float, __builtin_amdgcn_update_dpp(0, x, 0x111, 0xf, 0xf, true)); v += t;
    x = __builtin_bit_cast(int, v);
    t = __builtin_bit_cast(float, __builtin_amdgcn_update_dpp(0, x, 0x112, 0xf, 0xf, true)); v += t;
    x = __builtin_bit_cast(int, v);
    t = __builtin_bit_cast(float, __builtin_amdgcn_update_dpp(0, x, 0x114, 0xf, 0xf, true)); v += t;
    x = __builtin_bit_cast(int, v);
    t = __builtin_bit_cast(float, __builtin_amdgcn_update_dpp(0, x, 0x118, 0xf, 0xf, true)); v += t;
    x = __builtin_bit_cast(int, v);
    t = __builtin_bit_cast(float, __builtin_amdgcn_update_dpp(0, x, 0x142, 0xa, 0xf, true)); v += t;
    x = __builtin_bit_cast(int, v);
    t = __builtin_bit_cast(float, __builtin_amdgcn_update_dpp(0, x, 0x143, 0xc, 0xf, true)); v += t;
    return __builtin_bit_cast(float, __builtin_amdgcn_readlane(__builtin_bit_cast(int, v), 63));
}

// ---------------------------------------------------------------------------
// Custom monotonic grid barrier (R7). Replaces grid.sync(): one release-
// atomicAdd per block on a never-reset counter, tid0 spins with acquire
// loads until cnt >= 64*(g+1), then __syncthreads releases the block.
// Acq/rel on the counter gives the cb ping-pong the same cross-block
// visibility grid.sync provided (a block re-writes cb[g&1] only after all
// blocks passed barrier g+1, i.e. after all finished reading it).
// Cooperative launch is kept purely for the co-residency guarantee.
// ---------------------------------------------------------------------------
__device__ __forceinline__ void grid_barrier(int* cnt, int target) {
    __syncthreads();   // all block stores drained (vmcnt0 before s_barrier)
    if (threadIdx.x == 0) {
        __hip_atomic_fetch_add(cnt, 1, __ATOMIC_RELEASE, __HIP_MEMORY_SCOPE_AGENT);
        while (__hip_atomic_load(cnt, __ATOMIC_ACQUIRE, __HIP_MEMORY_SCOPE_AGENT) < target)
            __builtin_amdgcn_s_sleep(1);
    }
    __syncthreads();
}

// ---------------------------------------------------------------------------
// Kernel 2 (cooperative): sinkhorn + top-2 + softmax gather.
// R7 change: grid.sync() -> grid_barrier (everything else identical to R5;
// same arithmetic, same iteration count, bit-identical output).
// Grid = 64 blocks x 1024 threads. Wave w owns tokens b*256+w*16..+15;
// lane = expert. cost in registers.
// ---------------------------------------------------------------------------
__global__ __launch_bounds__(1024) void sinkhorn_router(const float* __restrict__ L,
                                                        float* __restrict__ colbuf,
                                                        int* __restrict__ cnt,
                                                        float* __restrict__ out,
                                                        int nh) {
    __shared__ float part[16][64];
    __shared__ float redq[64][17];
    __shared__ float d1s[64];
    __shared__ float err_s;

    const int b     = blockIdx.x;   // 0..63
    const int tid   = (int)threadIdx.x;
    const int w     = tid >> 6;     // wave 0..15
    const int lane  = tid & 63;     // expert index
    const int tbase = b * 256 + w * 16;

    float logit[16], cost[16], dreg[16];
#pragma unroll
    for (int j = 0; j < 16; ++j) {
        const int t = tbase + j;
        float l = L[(size_t)t * NEXP + lane];
        for (int h = 1; h < nh; ++h)
            l += L[(size_t)h * NTOK * NEXP + (size_t)t * NEXP + lane];
        logit[j] = l;
        cost[j]  = expf(l);
        dreg[j]  = 0.0f;
    }

    float d1l   = 1.0f;   // this lane's d1[e]
    float d1old = 1.0f;   // previous d1 (used by tid<64 for err)
    int   g     = 0;

    for (;;) {
        // ---- phase A: d0 per token (DPP reduce) + per-wave column partials
        float colacc = 0.0f;
#pragma unroll
        for (int j = 0; j < 16; ++j) {
            const float s = wave_sum64(d1l * cost[j]);   // wave-uniform
            const float d0 = (1.0f / 16384.0f) / (s + EPSF);
            dreg[j] = d0;
            colacc = fmaf(d0, cost[j], colacc);
        }
        part[w][lane] = colacc;
        __syncthreads();

        float* cb = colbuf + (size_t)(g & 1) * (NEXP * SBLK);
        if (tid < 64) {
            float s = part[0][tid];
#pragma unroll
            for (int q = 1; q < 16; ++q) s += part[q][tid];
            cb[tid * SBLK + b] = s;     // reader-coalesced layout [e][b]
        }
        grid_barrier(cnt, 64 * (g + 1));

        // ---- phase B: cross-block column reduction, all 1024 threads ----
        {
            const int e = tid >> 4;     // 0..63
            const int q = tid & 15;     // 0..15 -> blocks q*4..q*4+3
            const float4 v = *(const float4*)(cb + e * SBLK + q * 4);
            redq[e][q] = (v.x + v.y) + (v.z + v.w);
        }
        __syncthreads();

        if (tid < 64) {
            float tot = redq[tid][0];
#pragma unroll
            for (int q = 1; q < 16; ++q) tot += redq[tid][q];
            const float d1n = (1.0f / 64.0f) / (tot + EPSF);
            float diff = fabsf(d1old - d1n);
#pragma unroll
            for (int m = 32; m; m >>= 1) diff += __shfl_xor(diff, m, 64);
            d1s[tid] = d1n;
            d1old    = d1n;
            if (tid == 0) err_s = diff * (1.0f / 64.0f);
        }
        __syncthreads();
        d1l = d1s[lane];
        const float err = err_s;
        ++g;
        if (!(err > TOLF) || g >= 512) break;   // matches while(err>tol); NaN stops
    }

    // ---- final: per token top-2 of d1*cost*d0, softmax gather ----
#pragma unroll 1
    for (int j = 0; j < 16; ++j) {
        const int t = tbase + j;
        const float v = (d1l * cost[j]) * dreg[j];

        float bv = v; int bi = lane;
#pragma unroll
        for (int m = 32; m; m >>= 1) {
            const float ov = __shfl_xor(bv, m, 64);
            const int   oi = __shfl_xor(bi, m, 64);
            if (ov > bv || (ov == bv && oi < bi)) { bv = ov; bi = oi; }
        }
        const int i1 = bi;

        const float v2 = (lane == i1) ? -INFINITY : v;
        float bv2 = v2; int bi2 = lane;
#pragma unroll
        for (int m = 32; m; m >>= 1) {
            const float ov = __shfl_xor(bv2, m, 64);
            const int   oi = __shfl_xor(bi2, m, 64);
            if (ov > bv2 || (ov == bv2 && oi < bi2)) { bv2 = ov; bi2 = oi; }
        }
        const int i2 = bi2;

        float mx = logit[j];
#pragma unroll
        for (int m = 32; m; m >>= 1) mx = fmaxf(mx, __shfl_xor(mx, m, 64));
        const float e = expf(logit[j] - mx);
        float se = e;
#pragma unroll
        for (int m = 32; m; m >>= 1) se += __shfl_xor(se, m, 64);

        const float p1 = __shfl(e, i1, 64) / se;
        const float p2 = __shfl(e, i2, 64) / se;

        if (lane == 0) {
            out[(size_t)t * 2 + 0] = p1;
            out[(size_t)t * 2 + 1] = p2;
            out[(size_t)NTOK * 2 + (size_t)t * 2 + 0] = (float)i1;
            out[(size_t)NTOK * 2 + (size_t)t * 2 + 1] = (float)i2;
        }
    }
}

// ---------------------------------------------------------------------------
// ws layout (4.78 MB total, well under the proven-available 8.4 MB minimum):
//   [0,       256KB)  Wh f16 [64][2048]
//   [256KB,   512KB)  Wl f16 [64][2048] (pre-scaled x2048)
//   [512KB,   4.5MB)  L  f32 [16384][64]
//   [4.5MB,  +32KB )  colbuf (2 x 64 x 64 f32, sinkhorn ping-pong)
//   [+4B    )         barrier counter (zeroed by convert_w each launch)
// ---------------------------------------------------------------------------
extern "C" void kernel_launch(void* const* d_in, const int* in_sizes, int n_in,
                              void* d_out, int out_size, void* d_ws, size_t ws_size,
                              hipStream_t stream) {
    const float* x = (const float*)d_in[0];
    const float* W = (const float*)d_in[1];
    float* out = (float*)d_out;

    _Float16* Wh = (_Float16*)d_ws;
    _Float16* Wl = Wh + (size_t)NEXP * HID;                  // +131072 elems
    float* L      = (float*)((char*)d_ws + 524288);
    float* colbuf = L + (size_t)NTOK * NEXP;
    int*   cnt    = (int*)(colbuf + 2 * NEXP * SBLK);

    convert_w<<<dim3(64), dim3(256), 0, stream>>>(W, Wh, Wl, cnt);
    gemm_mfma<<<dim3(256), dim3(1024), 0, stream>>>(x, Wh, Wl, L);

    int nh = 1;
    void* args[] = { (void*)&L, (void*)&colbuf, (void*)&cnt, (void*)&out, (void*)&nh };
    hipLaunchCooperativeKernel((void*)sinkhorn_router, dim3(SBLK), dim3(1024),
                               args, 0, stream);
}

// Round 8
// 279.353 us; speedup vs baseline: 1.1590x; 1.0130x over previous
//
#include <hip/hip_runtime.h>
#include <hip/hip_cooperative_groups.h>
#include <math.h>

#define HID   2048
#define NEXP  64
#define NTOK  16384
#define SBLK  64      // sinkhorn blocks
#define TOLF  1e-4f
#define EPSF  1e-8f

typedef _Float16 f16x8 __attribute__((ext_vector_type(8)));
typedef float    f32x4 __attribute__((ext_vector_type(4)));

// ---------------------------------------------------------------------------
// Kernel 0: split W (64x2048 fp32) into Wh + Wl*2048 (f16, same [e][k] layout).
// Also zeroes the sinkhorn barrier counter (fresh per launch; the dispatch
// boundary is the release that makes it visible to sinkhorn_router).
// ---------------------------------------------------------------------------
__global__ __launch_bounds__(256) void convert_w(const float* __restrict__ W,
                                                 _Float16* __restrict__ Wh,
                                                 _Float16* __restrict__ Wl,
                                                 int* __restrict__ cnt) {
    if (blockIdx.x == 0 && threadIdx.x == 0) *cnt = 0;
    const int i = ((int)blockIdx.x * 256 + (int)threadIdx.x) * 8;
    const float4 w0 = *(const float4*)(W + i);
    const float4 w1 = *(const float4*)(W + i + 4);
    float v[8] = {w0.x, w0.y, w0.z, w0.w, w1.x, w1.y, w1.z, w1.w};
    f16x8 h, l;
#pragma unroll
    for (int j = 0; j < 8; ++j) {
        const _Float16 hh = (_Float16)v[j];
        h[j] = hh;
        l[j] = (_Float16)((v[j] - (float)hh) * 2048.0f);
    }
    *(f16x8*)(Wh + i) = h;
    *(f16x8*)(Wl + i) = l;
}

// ---------------------------------------------------------------------------
// Kernel 1: f16x3 MFMA logits, DOUBLE-BUFFERED LDS B (R8).
// R7 post-mortem: R4 structure = 2 barriers/chunk x 16 chunks, and hipcc
// drains vmcnt(0) at every barrier -> each chunk serially pays the full
// global round trip (~10K cyc/chunk vs ~4K work). Fix: buf[c&1] ping-pong,
// ONE barrier per chunk (31 -> 17); staging regs for chunk c+2 issued at
// the top of chunk c and written to LDS in the tail after the barrier --
// the vmcnt drain now lands ~a full compute phase after issue.
// Race check: write(tail of c, buf[c&1]) vs read(iter c+2, buf[c&1]) are
// separated by barrier(end of c+1); reads of buf[(c+1)&1] in iter c+1
// touch the other buffer. Accumulation order/MFMA schedule/epilogue are
// UNCHANGED from R4 -> bitwise-identical L.
// Grid = 256 x 1024 thr (16 waves = 4 token-groups x 4 k-slices).
// ---------------------------------------------------------------------------
#define BSTRIDE 40               // f16 per LDS B row (32 data + 8 pad)
#define BUFELTS (8 * 64 * BSTRIDE)   // 4 wk x 2(h/l) x 64 rows x 40 = 20480 f16

__global__ __launch_bounds__(1024, 4) void gemm_mfma(const float* __restrict__ x,
                                                     const _Float16* __restrict__ Wh,
                                                     const _Float16* __restrict__ Wl,
                                                     float* __restrict__ L) {
    // 80 KB static LDS: two 40960 B B-buffers during the loop,
    // red[16][1024] f32 (64 KB) in the epilogue (aliased; safe after the
    // final barrier of the loop).
    __shared__ __align__(16) char smem[81920];
    _Float16* Bs0 = (_Float16*)smem;
    _Float16* Bs1 = Bs0 + BUFELTS;
    float*    red = (float*)smem;

    const int tid    = (int)threadIdx.x;
    const int waveid = tid >> 6;       // 0..15
    const int wt     = waveid >> 2;    // token group 0..3 (16 tokens each)
    const int wk     = waveid & 3;     // k-slice 0..3 (512 k each)
    const int lane   = tid & 63;
    const int lo     = lane & 15;      // token row (A) / expert col (D)
    const int hi     = lane >> 4;      // k-block 0..3
    const int t0     = (int)blockIdx.x * 64;
    const int kb     = wk * 512;

    const int gt    = wt * 64 + lane;  // group-local tid
    const int sa    = gt >> 7;         // 0 = Wh, 1 = Wl
    const int srow  = (gt & 127) >> 1; // 0..63
    const int shalf = (gt & 1) * 16;   // 0 or 16 (f16)
    const _Float16* sgp = (sa ? Wl : Wh) + (size_t)srow * HID + kb + shalf;
    const int swbase = ((wk * 2 + sa) * 64 + srow) * BSTRIDE + shalf;

    const float* xp = x + (size_t)(t0 + wt * 16 + lo) * HID + kb + hi * 8;

    f32x4 acc_hh[4], acc_hl[4];
#pragma unroll
    for (int n = 0; n < 4; ++n) {
        acc_hh[n] = f32x4{0.f, 0.f, 0.f, 0.f};
        acc_hl[n] = f32x4{0.f, 0.f, 0.f, 0.f};
    }

    // prologue: stage chunks 0 and 1 into buf0/buf1
    {
        f16x8 p0 = *(const f16x8*)(sgp);
        f16x8 p1 = *(const f16x8*)(sgp + 8);
        f16x8 q0 = *(const f16x8*)(sgp + 32);
        f16x8 q1 = *(const f16x8*)(sgp + 40);
        *(f16x8*)&Bs0[swbase]     = p0;
        *(f16x8*)&Bs0[swbase + 8] = p1;
        *(f16x8*)&Bs1[swbase]     = q0;
        *(f16x8*)&Bs1[swbase + 8] = q1;
    }

    // 1-step-ahead A prefetch
    float4 a0n = *(const float4*)(xp);
    float4 a1n = *(const float4*)(xp + 4);
    __syncthreads();

    f16x8 sr0, sr1;   // staging regs for chunk c+2 (issued top-of-c)

#pragma unroll 2
    for (int c = 0; c < 16; ++c) {
        // issue chunk c+2's staging loads (consumed in this chunk's tail)
        if (c + 2 < 16) {
            sr0 = *(const f16x8*)(sgp + (c + 2) * 32);
            sr1 = *(const f16x8*)(sgp + (c + 2) * 32 + 8);
        }

        const float4 a0 = a0n, a1 = a1n;
        const int ko = ((c + 1 < 16) ? (c + 1) : 15) * 32;
        a0n = *(const float4*)(xp + ko);
        a1n = *(const float4*)(xp + ko + 4);

        // B fragments from the current buffer
        const _Float16* Bc = (c & 1) ? Bs1 : Bs0;
        f16x8 bh[4], bl[4];
#pragma unroll
        for (int n = 0; n < 4; ++n) {
            bh[n] = *(const f16x8*)&Bc[((wk * 2 + 0) * 64 + lo + n * 16) * BSTRIDE + hi * 8];
            bl[n] = *(const f16x8*)&Bc[((wk * 2 + 1) * 64 + lo + n * 16) * BSTRIDE + hi * 8];
        }

        // split current A chunk: xh (RTN) + xl*2048 (residual exact)
        f16x8 ah, al;
        const float av[8] = {a0.x, a0.y, a0.z, a0.w, a1.x, a1.y, a1.z, a1.w};
#pragma unroll
        for (int j = 0; j < 8; ++j) {
            const _Float16 hh = (_Float16)av[j];
            ah[j] = hh;
            al[j] = (_Float16)((av[j] - (float)hh) * 2048.0f);
        }

        // 12 MFMA; dependent acc_hl pairs separated by independent MFMAs
#pragma unroll
        for (int n = 0; n < 4; ++n)
            acc_hh[n] = __builtin_amdgcn_mfma_f32_16x16x32_f16(ah, bh[n], acc_hh[n], 0, 0, 0);
#pragma unroll
        for (int n = 0; n < 4; ++n)
            acc_hl[n] = __builtin_amdgcn_mfma_f32_16x16x32_f16(ah, bl[n], acc_hl[n], 0, 0, 0);
#pragma unroll
        for (int n = 0; n < 4; ++n)
            acc_hl[n] = __builtin_amdgcn_mfma_f32_16x16x32_f16(al, bh[n], acc_hl[n], 0, 0, 0);

        __syncthreads();   // all waves done reading buf[c&1]

        // tail: write chunk c+2 into the buffer just vacated
        if (c + 2 < 16) {
            _Float16* Bw = (c & 1) ? Bs1 : Bs0;
            *(f16x8*)&Bw[swbase]     = sr0;
            *(f16x8*)&Bw[swbase + 8] = sr1;
        }
    }

    // epilogue: per-wave partials -> red (aliases both B buffers; all B
    // reads completed before the loop's final barrier)
#pragma unroll
    for (int n = 0; n < 4; ++n)
#pragma unroll
        for (int r = 0; r < 4; ++r)
            red[waveid * 1024 + n * 256 + r * 64 + lane] =
                acc_hh[n][r] + acc_hl[n][r] * (1.0f / 2048.0f);
    __syncthreads();

    // cross-wk reduce + coalesced write (unchanged mapping)
    {
        const int o      = tid * 4;
        const int t_loc  = o >> 6;
        const int e      = o & 63;
        const int wt_src = t_loc >> 4;
        const int tl     = t_loc & 15;
        const int idx    = (e >> 4) * 256 + (tl & 3) * 64 + (tl >> 2) * 16 + (e & 15);
        float4 s = *(const float4*)&red[(wt_src * 4 + 0) * 1024 + idx];
#pragma unroll
        for (int q = 1; q < 4; ++q) {
            const float4 v = *(const float4*)&red[(wt_src * 4 + q) * 1024 + idx];
            s.x += v.x; s.y += v.y; s.z += v.z; s.w += v.w;
        }
        *(float4*)(L + (size_t)(t0 + t_loc) * NEXP + e) = s;
    }
}

// ---------------------------------------------------------------------------
// wave-wide f32 sum via DPP (VALU-only). row_shr 1/2/4/8 within 16-lane rows,
// row_bcast15/31 merge rows; lane 63 holds total; readlane -> wave-uniform.
// ---------------------------------------------------------------------------
__device__ __forceinline__ float wave_sum64(float v) {
    int x;
    float t;
    x = __builtin_bit_cast(int, v);
    t = __builtin_bit_cast(float, __builtin_amdgcn_update_dpp(0, x, 0x111, 0xf, 0xf, true)); v += t;
    x = __builtin_bit_cast(int, v);
    t = __builtin_bit_cast(float, __builtin_amdgcn_update_dpp(0, x, 0x112, 0xf, 0xf, true)); v += t;
    x = __builtin_bit_cast(int, v);
    t = __builtin_bit_cast(float, __builtin_amdgcn_update_dpp(0, x, 0x114, 0xf, 0xf, true)); v += t;
    x = __builtin_bit_cast(int, v);
    t = __builtin_bit_cast(float, __builtin_amdgcn_update_dpp(0, x, 0x118, 0xf, 0xf, true)); v += t;
    x = __builtin_bit_cast(int, v);
    t = __builtin_bit_cast(float, __builtin_amdgcn_update_dpp(0, x, 0x142, 0xa, 0xf, true)); v += t;
    x = __builtin_bit_cast(int, v);
    t = __builtin_bit_cast(float, __builtin_amdgcn_update_dpp(0, x, 0x143, 0xc, 0xf, true)); v += t;
    return __builtin_bit_cast(float, __builtin_amdgcn_readlane(__builtin_bit_cast(int, v), 63));
}

// ---------------------------------------------------------------------------
// Custom monotonic grid barrier (R7, kept): one release-atomicAdd per block
// on a never-reset counter; tid0 spins with acquire loads until
// cnt >= 64*(g+1); __syncthreads releases the block. Cooperative launch is
// kept purely for the co-residency guarantee.
// ---------------------------------------------------------------------------
__device__ __forceinline__ void grid_barrier(int* cnt, int target) {
    __syncthreads();
    if (threadIdx.x == 0) {
        __hip_atomic_fetch_add(cnt, 1, __ATOMIC_RELEASE, __HIP_MEMORY_SCOPE_AGENT);
        while (__hip_atomic_load(cnt, __ATOMIC_ACQUIRE, __HIP_MEMORY_SCOPE_AGENT) < target)
            __builtin_amdgcn_s_sleep(1);
    }
    __syncthreads();
}

// ---------------------------------------------------------------------------
// Kernel 2 (cooperative): sinkhorn + top-2 + softmax gather. UNCHANGED from
// R7 (isolating the gemm change). Grid = 64 blocks x 1024 threads.
// ---------------------------------------------------------------------------
__global__ __launch_bounds__(1024) void sinkhorn_router(const float* __restrict__ L,
                                                        float* __restrict__ colbuf,
                                                        int* __restrict__ cnt,
                                                        float* __restrict__ out,
                                                        int nh) {
    __shared__ float part[16][64];
    __shared__ float redq[64][17];
    __shared__ float d1s[64];
    __shared__ float err_s;

    const int b     = blockIdx.x;   // 0..63
    const int tid   = (int)threadIdx.x;
    const int w     = tid >> 6;     // wave 0..15
    const int lane  = tid & 63;     // expert index
    const int tbase = b * 256 + w * 16;

    float logit[16], cost[16], dreg[16];
#pragma unroll
    for (int j = 0; j < 16; ++j) {
        const int t = tbase + j;
        float l = L[(size_t)t * NEXP + lane];
        for (int h = 1; h < nh; ++h)
            l += L[(size_t)h * NTOK * NEXP + (size_t)t * NEXP + lane];
        logit[j] = l;
        cost[j]  = expf(l);
        dreg[j]  = 0.0f;
    }

    float d1l   = 1.0f;   // this lane's d1[e]
    float d1old = 1.0f;   // previous d1 (used by tid<64 for err)
    int   g     = 0;

    for (;;) {
        // ---- phase A: d0 per token (DPP reduce) + per-wave column partials
        float colacc = 0.0f;
#pragma unroll
        for (int j = 0; j < 16; ++j) {
            const float s = wave_sum64(d1l * cost[j]);   // wave-uniform
            const float d0 = (1.0f / 16384.0f) / (s + EPSF);
            dreg[j] = d0;
            colacc = fmaf(d0, cost[j], colacc);
        }
        part[w][lane] = colacc;
        __syncthreads();

        float* cb = colbuf + (size_t)(g & 1) * (NEXP * SBLK);
        if (tid < 64) {
            float s = part[0][tid];
#pragma unroll
            for (int q = 1; q < 16; ++q) s += part[q][tid];
            cb[tid * SBLK + b] = s;     // reader-coalesced layout [e][b]
        }
        grid_barrier(cnt, 64 * (g + 1));

        // ---- phase B: cross-block column reduction, all 1024 threads ----
        {
            const int e = tid >> 4;     // 0..63
            const int q = tid & 15;     // 0..15 -> blocks q*4..q*4+3
            const float4 v = *(const float4*)(cb + e * SBLK + q * 4);
            redq[e][q] = (v.x + v.y) + (v.z + v.w);
        }
        __syncthreads();

        if (tid < 64) {
            float tot = redq[tid][0];
#pragma unroll
            for (int q = 1; q < 16; ++q) tot += redq[tid][q];
            const float d1n = (1.0f / 64.0f) / (tot + EPSF);
            float diff = fabsf(d1old - d1n);
#pragma unroll
            for (int m = 32; m; m >>= 1) diff += __shfl_xor(diff, m, 64);
            d1s[tid] = d1n;
            d1old    = d1n;
            if (tid == 0) err_s = diff * (1.0f / 64.0f);
        }
        __syncthreads();
        d1l = d1s[lane];
        const float err = err_s;
        ++g;
        if (!(err > TOLF) || g >= 512) break;   // matches while(err>tol); NaN stops
    }

    // ---- final: per token top-2 of d1*cost*d0, softmax gather ----
#pragma unroll 1
    for (int j = 0; j < 16; ++j) {
        const int t = tbase + j;
        const float v = (d1l * cost[j]) * dreg[j];

        float bv = v; int bi = lane;
#pragma unroll
        for (int m = 32; m; m >>= 1) {
            const float ov = __shfl_xor(bv, m, 64);
            const int   oi = __shfl_xor(bi, m, 64);
            if (ov > bv || (ov == bv && oi < bi)) { bv = ov; bi = oi; }
        }
        const int i1 = bi;

        const float v2 = (lane == i1) ? -INFINITY : v;
        float bv2 = v2; int bi2 = lane;
#pragma unroll
        for (int m = 32; m; m >>= 1) {
            const float ov = __shfl_xor(bv2, m, 64);
            const int   oi = __shfl_xor(bi2, m, 64);
            if (ov > bv2 || (ov == bv2 && oi < bi2)) { bv2 = ov; bi2 = oi; }
        }
        const int i2 = bi2;

        float mx = logit[j];
#pragma unroll
        for (int m = 32; m; m >>= 1) mx = fmaxf(mx, __shfl_xor(mx, m, 64));
        const float e = expf(logit[j] - mx);
        float se = e;
#pragma unroll
        for (int m = 32; m; m >>= 1) se += __shfl_xor(se, m, 64);

        const float p1 = __shfl(e, i1, 64) / se;
        const float p2 = __shfl(e, i2, 64) / se;

        if (lane == 0) {
            out[(size_t)t * 2 + 0] = p1;
            out[(size_t)t * 2 + 1] = p2;
            out[(size_t)NTOK * 2 + (size_t)t * 2 + 0] = (float)i1;
            out[(size_t)NTOK * 2 + (size_t)t * 2 + 1] = (float)i2;
        }
    }
}

// ---------------------------------------------------------------------------
// ws layout (4.78 MB total, well under the proven-available 8.4 MB minimum):
//   [0,       256KB)  Wh f16 [64][2048]
//   [256KB,   512KB)  Wl f16 [64][2048] (pre-scaled x2048)
//   [512KB,   4.5MB)  L  f32 [16384][64]
//   [4.5MB,  +32KB )  colbuf (2 x 64 x 64 f32, sinkhorn ping-pong)
//   [+4B    )         barrier counter (zeroed by convert_w each launch)
// ---------------------------------------------------------------------------
extern "C" void kernel_launch(void* const* d_in, const int* in_sizes, int n_in,
                              void* d_out, int out_size, void* d_ws, size_t ws_size,
                              hipStream_t stream) {
    const float* x = (const float*)d_in[0];
    const float* W = (const float*)d_in[1];
    float* out = (float*)d_out;

    _Float16* Wh = (_Float16*)d_ws;
    _Float16* Wl = Wh + (size_t)NEXP * HID;                  // +131072 elems
    float* L      = (float*)((char*)d_ws + 524288);
    float* colbuf = L + (size_t)NTOK * NEXP;
    int*   cnt    = (int*)(colbuf + 2 * NEXP * SBLK);

    convert_w<<<dim3(64), dim3(256), 0, stream>>>(W, Wh, Wl, cnt);
    gemm_mfma<<<dim3(256), dim3(1024), 0, stream>>>(x, Wh, Wl, L);

    int nh = 1;
    void* args[] = { (void*)&L, (void*)&colbuf, (void*)&cnt, (void*)&out, (void*)&nh };
    hipLaunchCooperativeKernel((void*)sinkhorn_router, dim3(SBLK), dim3(1024),
                               args, 0, stream);
}

// Round 9
// 274.788 us; speedup vs baseline: 1.1783x; 1.0166x over previous
//
#include <hip/hip_runtime.h>
#include <hip/hip_cooperative_groups.h>
#include <math.h>

#define HID   2048
#define NEXP  64
#define NTOK  16384
#define SBLK  64      // sinkhorn blocks
#define TOLF  1e-4f
#define EPSF  1e-8f

typedef _Float16 f16x8 __attribute__((ext_vector_type(8)));
typedef float    f32x4 __attribute__((ext_vector_type(4)));

// ---------------------------------------------------------------------------
// f16x3 split of 8 fp32 values: h = RTN f32->f16, l = (v - h) * 2048 (exact
// residual, Sterbenz). Same math as the old convert_w kernel -> identical
// Wh/Wl values -> bitwise-identical L.
// ---------------------------------------------------------------------------
__device__ __forceinline__ void cvt8(const float4 a, const float4 b,
                                     f16x8& h, f16x8& l) {
    const float v[8] = {a.x, a.y, a.z, a.w, b.x, b.y, b.z, b.w};
#pragma unroll
    for (int j = 0; j < 8; ++j) {
        const _Float16 hh = (_Float16)v[j];
        h[j] = hh;
        l[j] = (_Float16)((v[j] - (float)hh) * 2048.0f);
    }
}

// ---------------------------------------------------------------------------
// Kernel 1: f16x3 MFMA logits, double-buffered LDS B (R8 structure, banked
// at ~65us). R9 change: convert_w FOLDED into staging -- each thread loads
// its 32B W row-fragment as fp32 (2 x float4, same byte count as before)
// and does the h/l split in the staging tail. One fewer dispatch; Wh/Wl
// ws buffers gone. Also zeroes the sinkhorn barrier counter (block 0).
// Grid = 256 x 1024 thr (16 waves = 4 token-groups x 4 k-slices).
// ---------------------------------------------------------------------------
#define BSTRIDE 40               // f16 per LDS B row (32 data + 8 pad)
#define BUFELTS (8 * 64 * BSTRIDE)   // 4 wk x 2(h/l) x 64 rows x 40 = 20480 f16

__global__ __launch_bounds__(1024, 4) void gemm_mfma(const float* __restrict__ x,
                                                     const float* __restrict__ W,
                                                     float* __restrict__ L,
                                                     int* __restrict__ cnt) {
    // 80 KB static LDS: two 40960 B B-buffers during the loop,
    // red[16][1024] f32 (64 KB) in the epilogue (aliased; safe after the
    // final barrier of the loop).
    __shared__ __align__(16) char smem[81920];
    _Float16* Bs0 = (_Float16*)smem;
    _Float16* Bs1 = Bs0 + BUFELTS;
    float*    red = (float*)smem;

    const int tid    = (int)threadIdx.x;
    if (blockIdx.x == 0 && tid == 0) *cnt = 0;   // barrier counter reset

    const int waveid = tid >> 6;       // 0..15
    const int wt     = waveid >> 2;    // token group 0..3 (16 tokens each)
    const int wk     = waveid & 3;     // k-slice 0..3 (512 k each)
    const int lane   = tid & 63;
    const int lo     = lane & 15;      // token row (A) / expert col (D)
    const int hi     = lane >> 4;      // k-block 0..3
    const int t0     = (int)blockIdx.x * 64;
    const int kb     = wk * 512;

    // staging: group-local thread gt (0..255) owns row srow, frag sfrag
    // (8 fp32 = 32B in, 8+8 f16 out to the h-row and l-row).
    const int gt    = wt * 64 + lane;
    const int srow  = gt >> 2;         // 0..63
    const int sfrag = gt & 3;          // 0..3 -> floats sfrag*8..+7
    const float* sgp = W + (size_t)srow * HID + kb + sfrag * 8;
    const int swh = ((wk * 2 + 0) * 64 + srow) * BSTRIDE + sfrag * 8;
    const int swl = ((wk * 2 + 1) * 64 + srow) * BSTRIDE + sfrag * 8;

    const float* xp = x + (size_t)(t0 + wt * 16 + lo) * HID + kb + hi * 8;

    f32x4 acc_hh[4], acc_hl[4];
#pragma unroll
    for (int n = 0; n < 4; ++n) {
        acc_hh[n] = f32x4{0.f, 0.f, 0.f, 0.f};
        acc_hl[n] = f32x4{0.f, 0.f, 0.f, 0.f};
    }

    // prologue: stage chunks 0 and 1 into buf0/buf1 (convert on the fly)
    {
        const float4 v0 = *(const float4*)(sgp);
        const float4 v1 = *(const float4*)(sgp + 4);
        const float4 v2 = *(const float4*)(sgp + 32);
        const float4 v3 = *(const float4*)(sgp + 36);
        f16x8 h, l;
        cvt8(v0, v1, h, l);
        *(f16x8*)&Bs0[swh] = h;
        *(f16x8*)&Bs0[swl] = l;
        cvt8(v2, v3, h, l);
        *(f16x8*)&Bs1[swh] = h;
        *(f16x8*)&Bs1[swl] = l;
    }

    // 1-step-ahead A prefetch
    float4 a0n = *(const float4*)(xp);
    float4 a1n = *(const float4*)(xp + 4);
    __syncthreads();

    float4 sv0, sv1;   // fp32 staging regs for chunk c+2 (issued top-of-c)

#pragma unroll 2
    for (int c = 0; c < 16; ++c) {
        // issue chunk c+2's staging loads (consumed in this chunk's tail)
        if (c + 2 < 16) {
            sv0 = *(const float4*)(sgp + (c + 2) * 32);
            sv1 = *(const float4*)(sgp + (c + 2) * 32 + 4);
        }

        const float4 a0 = a0n, a1 = a1n;
        const int ko = ((c + 1 < 16) ? (c + 1) : 15) * 32;
        a0n = *(const float4*)(xp + ko);
        a1n = *(const float4*)(xp + ko + 4);

        // B fragments from the current buffer
        const _Float16* Bc = (c & 1) ? Bs1 : Bs0;
        f16x8 bh[4], bl[4];
#pragma unroll
        for (int n = 0; n < 4; ++n) {
            bh[n] = *(const f16x8*)&Bc[((wk * 2 + 0) * 64 + lo + n * 16) * BSTRIDE + hi * 8];
            bl[n] = *(const f16x8*)&Bc[((wk * 2 + 1) * 64 + lo + n * 16) * BSTRIDE + hi * 8];
        }

        // split current A chunk: xh (RTN) + xl*2048 (residual exact)
        f16x8 ah, al;
        const float av[8] = {a0.x, a0.y, a0.z, a0.w, a1.x, a1.y, a1.z, a1.w};
#pragma unroll
        for (int j = 0; j < 8; ++j) {
            const _Float16 hh = (_Float16)av[j];
            ah[j] = hh;
            al[j] = (_Float16)((av[j] - (float)hh) * 2048.0f);
        }

        // 12 MFMA; dependent acc_hl pairs separated by independent MFMAs
#pragma unroll
        for (int n = 0; n < 4; ++n)
            acc_hh[n] = __builtin_amdgcn_mfma_f32_16x16x32_f16(ah, bh[n], acc_hh[n], 0, 0, 0);
#pragma unroll
        for (int n = 0; n < 4; ++n)
            acc_hl[n] = __builtin_amdgcn_mfma_f32_16x16x32_f16(ah, bl[n], acc_hl[n], 0, 0, 0);
#pragma unroll
        for (int n = 0; n < 4; ++n)
            acc_hl[n] = __builtin_amdgcn_mfma_f32_16x16x32_f16(al, bh[n], acc_hl[n], 0, 0, 0);

        __syncthreads();   // all waves done reading buf[c&1]

        // tail: convert + write chunk c+2 into the buffer just vacated
        if (c + 2 < 16) {
            _Float16* Bw = (c & 1) ? Bs1 : Bs0;
            f16x8 h, l;
            cvt8(sv0, sv1, h, l);
            *(f16x8*)&Bw[swh] = h;
            *(f16x8*)&Bw[swl] = l;
        }
    }

    // epilogue: per-wave partials -> red (aliases both B buffers; all B
    // reads completed before the loop's final barrier)
#pragma unroll
    for (int n = 0; n < 4; ++n)
#pragma unroll
        for (int r = 0; r < 4; ++r)
            red[waveid * 1024 + n * 256 + r * 64 + lane] =
                acc_hh[n][r] + acc_hl[n][r] * (1.0f / 2048.0f);
    __syncthreads();

    // cross-wk reduce + coalesced write (unchanged mapping)
    {
        const int o      = tid * 4;
        const int t_loc  = o >> 6;
        const int e      = o & 63;
        const int wt_src = t_loc >> 4;
        const int tl     = t_loc & 15;
        const int idx    = (e >> 4) * 256 + (tl & 3) * 64 + (tl >> 2) * 16 + (e & 15);
        float4 s = *(const float4*)&red[(wt_src * 4 + 0) * 1024 + idx];
#pragma unroll
        for (int q = 1; q < 4; ++q) {
            const float4 v = *(const float4*)&red[(wt_src * 4 + q) * 1024 + idx];
            s.x += v.x; s.y += v.y; s.z += v.z; s.w += v.w;
        }
        *(float4*)(L + (size_t)(t0 + t_loc) * NEXP + e) = s;
    }
}

// ---------------------------------------------------------------------------
// wave-wide f32 sum via DPP (VALU-only). row_shr 1/2/4/8 within 16-lane rows,
// row_bcast15/31 merge rows; lane 63 holds total; readlane -> wave-uniform.
// ---------------------------------------------------------------------------
__device__ __forceinline__ float wave_sum64(float v) {
    int x;
    float t;
    x = __builtin_bit_cast(int, v);
    t = __builtin_bit_cast(float, __builtin_amdgcn_update_dpp(0, x, 0x111, 0xf, 0xf, true)); v += t;
    x = __builtin_bit_cast(int, v);
    t = __builtin_bit_cast(float, __builtin_amdgcn_update_dpp(0, x, 0x112, 0xf, 0xf, true)); v += t;
    x = __builtin_bit_cast(int, v);
    t = __builtin_bit_cast(float, __builtin_amdgcn_update_dpp(0, x, 0x114, 0xf, 0xf, true)); v += t;
    x = __builtin_bit_cast(int, v);
    t = __builtin_bit_cast(float, __builtin_amdgcn_update_dpp(0, x, 0x118, 0xf, 0xf, true)); v += t;
    x = __builtin_bit_cast(int, v);
    t = __builtin_bit_cast(float, __builtin_amdgcn_update_dpp(0, x, 0x142, 0xa, 0xf, true)); v += t;
    x = __builtin_bit_cast(int, v);
    t = __builtin_bit_cast(float, __builtin_amdgcn_update_dpp(0, x, 0x143, 0xc, 0xf, true)); v += t;
    return __builtin_bit_cast(float, __builtin_amdgcn_readlane(__builtin_bit_cast(int, v), 63));
}

// ---------------------------------------------------------------------------
// Custom monotonic grid barrier, R9 version. R7/R8 spun with ACQUIRE loads:
// each poll emits an L2-invalidate on gfx950 (agent-scope acquire) -- tens
// of polls x 64 blocks x 25 iters of pure cache-op overhead, also trashing
// the XCD L2 for co-located blocks. Now: spin on RELAXED loads, escalating
// to an ACQUIRE load every 8th poll (deadlock-proof even if relaxed loads
// can be served stale by the non-coherent L2). The final ACQUIRE load
// establishes synchronizes-with against ALL arrivals (atomic RMWs extend
// the release sequence), so colbuf reads after the barrier are ordered.
// ---------------------------------------------------------------------------
__device__ __forceinline__ void grid_barrier(int* cnt, int target) {
    __syncthreads();
    if (threadIdx.x == 0) {
        __hip_atomic_fetch_add(cnt, 1, __ATOMIC_RELEASE, __HIP_MEMORY_SCOPE_AGENT);
        int it = 0;
        for (;;) {
            int v = __hip_atomic_load(cnt, __ATOMIC_RELAXED, __HIP_MEMORY_SCOPE_AGENT);
            if (v >= target) break;
            if ((++it & 7) == 0) {
                v = __hip_atomic_load(cnt, __ATOMIC_ACQUIRE, __HIP_MEMORY_SCOPE_AGENT);
                if (v >= target) break;
            }
            __builtin_amdgcn_s_sleep(1);
        }
        (void)__hip_atomic_load(cnt, __ATOMIC_ACQUIRE, __HIP_MEMORY_SCOPE_AGENT);
    }
    __syncthreads();
}

// ---------------------------------------------------------------------------
// Kernel 2 (cooperative): sinkhorn + top-2 + softmax gather. Identical math
// to R7/R8 (bit-identical iterates); only the barrier internals changed.
// Grid = 64 blocks x 1024 threads. Wave w owns tokens b*256+w*16..+15;
// lane = expert. cost in registers.
// ---------------------------------------------------------------------------
__global__ __launch_bounds__(1024) void sinkhorn_router(const float* __restrict__ L,
                                                        float* __restrict__ colbuf,
                                                        int* __restrict__ cnt,
                                                        float* __restrict__ out,
                                                        int nh) {
    __shared__ float part[16][64];
    __shared__ float redq[64][17];
    __shared__ float d1s[64];
    __shared__ float err_s;

    const int b     = blockIdx.x;   // 0..63
    const int tid   = (int)threadIdx.x;
    const int w     = tid >> 6;     // wave 0..15
    const int lane  = tid & 63;     // expert index
    const int tbase = b * 256 + w * 16;

    float logit[16], cost[16], dreg[16];
#pragma unroll
    for (int j = 0; j < 16; ++j) {
        const int t = tbase + j;
        float l = L[(size_t)t * NEXP + lane];
        for (int h = 1; h < nh; ++h)
            l += L[(size_t)h * NTOK * NEXP + (size_t)t * NEXP + lane];
        logit[j] = l;
        cost[j]  = expf(l);
        dreg[j]  = 0.0f;
    }

    float d1l   = 1.0f;   // this lane's d1[e]
    float d1old = 1.0f;   // previous d1 (used by tid<64 for err)
    int   g     = 0;

    for (;;) {
        // ---- phase A: d0 per token (DPP reduce) + per-wave column partials
        float colacc = 0.0f;
#pragma unroll
        for (int j = 0; j < 16; ++j) {
            const float s = wave_sum64(d1l * cost[j]);   // wave-uniform
            const float d0 = (1.0f / 16384.0f) / (s + EPSF);
            dreg[j] = d0;
            colacc = fmaf(d0, cost[j], colacc);
        }
        part[w][lane] = colacc;
        __syncthreads();

        float* cb = colbuf + (size_t)(g & 1) * (NEXP * SBLK);
        if (tid < 64) {
            float s = part[0][tid];
#pragma unroll
            for (int q = 1; q < 16; ++q) s += part[q][tid];
            cb[tid * SBLK + b] = s;     // reader-coalesced layout [e][b]
        }
        grid_barrier(cnt, 64 * (g + 1));

        // ---- phase B: cross-block column reduction, all 1024 threads ----
        {
            const int e = tid >> 4;     // 0..63
            const int q = tid & 15;     // 0..15 -> blocks q*4..q*4+3
            const float4 v = *(const float4*)(cb + e * SBLK + q * 4);
            redq[e][q] = (v.x + v.y) + (v.z + v.w);
        }
        __syncthreads();

        if (tid < 64) {
            float tot = redq[tid][0];
#pragma unroll
            for (int q = 1; q < 16; ++q) tot += redq[tid][q];
            const float d1n = (1.0f / 64.0f) / (tot + EPSF);
            float diff = fabsf(d1old - d1n);
#pragma unroll
            for (int m = 32; m; m >>= 1) diff += __shfl_xor(diff, m, 64);
            d1s[tid] = d1n;
            d1old    = d1n;
            if (tid == 0) err_s = diff * (1.0f / 64.0f);
        }
        __syncthreads();
        d1l = d1s[lane];
        const float err = err_s;
        ++g;
        if (!(err > TOLF) || g >= 512) break;   // matches while(err>tol); NaN stops
    }

    // ---- final: per token top-2 of d1*cost*d0, softmax gather ----
#pragma unroll 1
    for (int j = 0; j < 16; ++j) {
        const int t = tbase + j;
        const float v = (d1l * cost[j]) * dreg[j];

        float bv = v; int bi = lane;
#pragma unroll
        for (int m = 32; m; m >>= 1) {
            const float ov = __shfl_xor(bv, m, 64);
            const int   oi = __shfl_xor(bi, m, 64);
            if (ov > bv || (ov == bv && oi < bi)) { bv = ov; bi = oi; }
        }
        const int i1 = bi;

        const float v2 = (lane == i1) ? -INFINITY : v;
        float bv2 = v2; int bi2 = lane;
#pragma unroll
        for (int m = 32; m; m >>= 1) {
            const float ov = __shfl_xor(bv2, m, 64);
            const int   oi = __shfl_xor(bi2, m, 64);
            if (ov > bv2 || (ov == bv2 && oi < bi2)) { bv2 = ov; bi2 = oi; }
        }
        const int i2 = bi2;

        float mx = logit[j];
#pragma unroll
        for (int m = 32; m; m >>= 1) mx = fmaxf(mx, __shfl_xor(mx, m, 64));
        const float e = expf(logit[j] - mx);
        float se = e;
#pragma unroll
        for (int m = 32; m; m >>= 1) se += __shfl_xor(se, m, 64);

        const float p1 = __shfl(e, i1, 64) / se;
        const float p2 = __shfl(e, i2, 64) / se;

        if (lane == 0) {
            out[(size_t)t * 2 + 0] = p1;
            out[(size_t)t * 2 + 1] = p2;
            out[(size_t)NTOK * 2 + (size_t)t * 2 + 0] = (float)i1;
            out[(size_t)NTOK * 2 + (size_t)t * 2 + 1] = (float)i2;
        }
    }
}

// ---------------------------------------------------------------------------
// ws layout (4.25 MB total; Wh/Wl buffers gone with the convert_w fold):
//   [0,      4.0MB)  L  f32 [16384][64]
//   [4.0MB, +32KB )  colbuf (2 x 64 x 64 f32, sinkhorn ping-pong)
//   [+4B   )         barrier counter (zeroed by gemm block 0 each launch)
// ---------------------------------------------------------------------------
extern "C" void kernel_launch(void* const* d_in, const int* in_sizes, int n_in,
                              void* d_out, int out_size, void* d_ws, size_t ws_size,
                              hipStream_t stream) {
    const float* x = (const float*)d_in[0];
    const float* W = (const float*)d_in[1];
    float* out = (float*)d_out;

    float* L      = (float*)d_ws;
    float* colbuf = L + (size_t)NTOK * NEXP;
    int*   cnt    = (int*)(colbuf + 2 * NEXP * SBLK);

    gemm_mfma<<<dim3(256), dim3(1024), 0, stream>>>(x, W, L, cnt);

    int nh = 1;
    void* args[] = { (void*)&L, (void*)&colbuf, (void*)&cnt, (void*)&out, (void*)&nh };
    hipLaunchCooperativeKernel((void*)sinkhorn_router, dim3(SBLK), dim3(1024),
                               args, 0, stream);
}

// Round 11
// 271.708 us; speedup vs baseline: 1.1916x; 1.0113x over previous
//
#include <hip/hip_runtime.h>
#include <hip/hip_cooperative_groups.h>
#include <math.h>

#define HID   2048
#define NEXP  64
#define NTOK  16384
#define SBLK  64      // sinkhorn blocks
#define TOLF  1e-4f
#define EPSF  1e-8f

typedef _Float16 f16x8 __attribute__((ext_vector_type(8)));
typedef float    f32x4 __attribute__((ext_vector_type(4)));

// ---------------------------------------------------------------------------
// f16x3 split of 8 fp32 values: h = RTN f32->f16, l = (v - h) * 2048 (exact
// residual, Sterbenz). Identical math every round -> bitwise-identical L.
// ---------------------------------------------------------------------------
__device__ __forceinline__ void cvt8(const float4 a, const float4 b,
                                     f16x8& h, f16x8& l) {
    const float v[8] = {a.x, a.y, a.z, a.w, b.x, b.y, b.z, b.w};
#pragma unroll
    for (int j = 0; j < 8; ++j) {
        const _Float16 hh = (_Float16)v[j];
        h[j] = hh;
        l[j] = (_Float16)((v[j] - (float)hh) * 2048.0f);
    }
}

// ---------------------------------------------------------------------------
// Kernel 1: f16x3 MFMA logits, double-buffered LDS B.
// R10 change: TAIL-ISSUE schedule. R9 post-mortem: ~9.8K cyc/chunk vs ~1.5K
// work because staging(c+2)/A(c+1) loads were issued at the TOP of chunk c
// and the barrier's vmcnt(0) at the bottom drained those fresh loads ->
// every chunk paid an HBM round trip in the barrier. Now ALL global loads
// are issued in the tail AFTER the barrier; at any barrier the outstanding
// loads are >=1 full compute phase old -> drain ~free. A regs are 2-deep
// (a_cur/a_nxt). Same accumulation order -> bitwise-identical L.
// Grid = 256 x 1024 thr (16 waves = 4 token-groups x 4 k-slices).
// Also zeroes the sinkhorn tree-barrier area (block 0).
// ---------------------------------------------------------------------------
#define BSTRIDE 40               // f16 per LDS B row (32 data + 8 pad)
#define BUFELTS (8 * 64 * BSTRIDE)   // 4 wk x 2(h/l) x 64 rows x 40 = 20480 f16
#define LEAFSTRIDE 32            // ints (128 B) between barrier counters

__global__ __launch_bounds__(1024, 4) void gemm_mfma(const float* __restrict__ x,
                                                     const float* __restrict__ W,
                                                     float* __restrict__ L,
                                                     int* __restrict__ cnt) {
    // 80 KB static LDS: two 40960 B B-buffers during the loop,
    // red[16][1024] f32 (64 KB) in the epilogue (aliased after final barrier).
    __shared__ __align__(16) char smem[81920];
    _Float16* Bs0 = (_Float16*)smem;
    _Float16* Bs1 = Bs0 + BUFELTS;
    float*    red = (float*)smem;

    const int tid = (int)threadIdx.x;
    if (blockIdx.x == 0 && tid < 10 * LEAFSTRIDE) cnt[tid] = 0;  // barrier area

    const int waveid = tid >> 6;       // 0..15
    const int wt     = waveid >> 2;    // token group 0..3 (16 tokens each)
    const int wk     = waveid & 3;     // k-slice 0..3 (512 k each)
    const int lane   = tid & 63;
    const int lo     = lane & 15;      // token row (A) / expert col (D)
    const int hi     = lane >> 4;      // k-block 0..3
    const int t0     = (int)blockIdx.x * 64;
    const int kb     = wk * 512;

    // staging: group-local thread gt owns row srow, frag sfrag (8 fp32 in,
    // 8+8 f16 out to the h-row and l-row).
    const int gt    = wt * 64 + lane;
    const int srow  = gt >> 2;         // 0..63
    const int sfrag = gt & 3;          // 0..3 -> floats sfrag*8..+7
    const float* sgp = W + (size_t)srow * HID + kb + sfrag * 8;
    const int swh = ((wk * 2 + 0) * 64 + srow) * BSTRIDE + sfrag * 8;
    const int swl = ((wk * 2 + 1) * 64 + srow) * BSTRIDE + sfrag * 8;

    const float* xp = x + (size_t)(t0 + wt * 16 + lo) * HID + kb + hi * 8;

    f32x4 acc_hh[4], acc_hl[4];
#pragma unroll
    for (int n = 0; n < 4; ++n) {
        acc_hh[n] = f32x4{0.f, 0.f, 0.f, 0.f};
        acc_hl[n] = f32x4{0.f, 0.f, 0.f, 0.f};
    }

    // ---- prologue: chunks 0,1 staged; A chunk0 (cur) + chunk1 (nxt);
    //      staging regs primed with chunk 2 BEFORE the first barrier (the
    //      one-time drain there is acceptable).
    float4 sv0 = *(const float4*)(sgp);
    float4 sv1 = *(const float4*)(sgp + 4);
    {
        const float4 t2 = *(const float4*)(sgp + 32);
        const float4 t3 = *(const float4*)(sgp + 36);
        f16x8 h, l;
        cvt8(sv0, sv1, h, l);
        *(f16x8*)&Bs0[swh] = h;
        *(f16x8*)&Bs0[swl] = l;
        cvt8(t2, t3, h, l);
        *(f16x8*)&Bs1[swh] = h;
        *(f16x8*)&Bs1[swl] = l;
    }
    float4 a0c = *(const float4*)(xp);
    float4 a1c = *(const float4*)(xp + 4);
    float4 a0n = *(const float4*)(xp + 32);
    float4 a1n = *(const float4*)(xp + 36);
    sv0 = *(const float4*)(sgp + 64);   // chunk 2 staging (written tail c=0)
    sv1 = *(const float4*)(sgp + 68);
    __syncthreads();

#pragma unroll 2
    for (int c = 0; c < 16; ++c) {
        // ---- compute phase: NO global issues here ----
        const _Float16* Bc = (c & 1) ? Bs1 : Bs0;
        f16x8 bh[4], bl[4];
#pragma unroll
        for (int n = 0; n < 4; ++n) {
            bh[n] = *(const f16x8*)&Bc[((wk * 2 + 0) * 64 + lo + n * 16) * BSTRIDE + hi * 8];
            bl[n] = *(const f16x8*)&Bc[((wk * 2 + 1) * 64 + lo + n * 16) * BSTRIDE + hi * 8];
        }

        f16x8 ah, al;
        const float av[8] = {a0c.x, a0c.y, a0c.z, a0c.w, a1c.x, a1c.y, a1c.z, a1c.w};
#pragma unroll
        for (int j = 0; j < 8; ++j) {
            const _Float16 hh = (_Float16)av[j];
            ah[j] = hh;
            al[j] = (_Float16)((av[j] - (float)hh) * 2048.0f);
        }

#pragma unroll
        for (int n = 0; n < 4; ++n)
            acc_hh[n] = __builtin_amdgcn_mfma_f32_16x16x32_f16(ah, bh[n], acc_hh[n], 0, 0, 0);
#pragma unroll
        for (int n = 0; n < 4; ++n)
            acc_hl[n] = __builtin_amdgcn_mfma_f32_16x16x32_f16(ah, bl[n], acc_hl[n], 0, 0, 0);
#pragma unroll
        for (int n = 0; n < 4; ++n)
            acc_hl[n] = __builtin_amdgcn_mfma_f32_16x16x32_f16(al, bh[n], acc_hl[n], 0, 0, 0);

        __syncthreads();   // drains only loads issued in tail(c-1): >=1 phase old

        // ---- tail: writes + ALL global issues for the next chunks ----
        if (c + 2 < 16) {              // write chunk c+2 (sv issued tail(c-1))
            _Float16* Bw = (c & 1) ? Bs1 : Bs0;
            f16x8 h, l;
            cvt8(sv0, sv1, h, l);
            *(f16x8*)&Bw[swh] = h;
            *(f16x8*)&Bw[swl] = l;
        }
        a0c = a0n; a1c = a1n;          // A chunk c+1 (issued tail(c-1))
        if (c + 2 < 16) {              // issue A chunk c+2
            a0n = *(const float4*)(xp + (c + 2) * 32);
            a1n = *(const float4*)(xp + (c + 2) * 32 + 4);
        }
        if (c + 3 < 16) {              // issue W chunk c+3 (written tail(c+1))
            sv0 = *(const float4*)(sgp + (c + 3) * 32);
            sv1 = *(const float4*)(sgp + (c + 3) * 32 + 4);
        }
    }

    // epilogue: per-wave partials -> red (aliases B buffers; barriered)
#pragma unroll
    for (int n = 0; n < 4; ++n)
#pragma unroll
        for (int r = 0; r < 4; ++r)
            red[waveid * 1024 + n * 256 + r * 64 + lane] =
                acc_hh[n][r] + acc_hl[n][r] * (1.0f / 2048.0f);
    __syncthreads();

    // cross-wk reduce + coalesced write (unchanged mapping)
    {
        const int o      = tid * 4;
        const int t_loc  = o >> 6;
        const int e      = o & 63;
        const int wt_src = t_loc >> 4;
        const int tl     = t_loc & 15;
        const int idx    = (e >> 4) * 256 + (tl & 3) * 64 + (tl >> 2) * 16 + (e & 15);
        float4 s = *(const float4*)&red[(wt_src * 4 + 0) * 1024 + idx];
#pragma unroll
        for (int q = 1; q < 4; ++q) {
            const float4 v = *(const float4*)&red[(wt_src * 4 + q) * 1024 + idx];
            s.x += v.x; s.y += v.y; s.z += v.z; s.w += v.w;
        }
        *(float4*)(L + (size_t)(t0 + t_loc) * NEXP + e) = s;
    }
}

// ---------------------------------------------------------------------------
// wave-wide f32 sum via DPP (VALU-only). row_shr 1/2/4/8 within 16-lane rows,
// row_bcast15/31 merge rows; lane 63 holds total; readlane -> wave-uniform.
// ---------------------------------------------------------------------------
__device__ __forceinline__ float wave_sum64(float v) {
    int x;
    float t;
    x = __builtin_bit_cast(int, v);
    t = __builtin_bit_cast(float, __builtin_amdgcn_update_dpp(0, x, 0x111, 0xf, 0xf, true)); v += t;
    x = __builtin_bit_cast(int, v);
    t = __builtin_bit_cast(float, __builtin_amdgcn_update_dpp(0, x, 0x112, 0xf, 0xf, true)); v += t;
    x = __builtin_bit_cast(int, v);
    t = __builtin_bit_cast(float, __builtin_amdgcn_update_dpp(0, x, 0x114, 0xf, 0xf, true)); v += t;
    x = __builtin_bit_cast(int, v);
    t = __builtin_bit_cast(float, __builtin_amdgcn_update_dpp(0, x, 0x118, 0xf, 0xf, true)); v += t;
    x = __builtin_bit_cast(int, v);
    t = __builtin_bit_cast(float, __builtin_amdgcn_update_dpp(0, x, 0x142, 0xa, 0xf, true)); v += t;
    x = __builtin_bit_cast(int, v);
    t = __builtin_bit_cast(float, __builtin_amdgcn_update_dpp(0, x, 0x143, 0xc, 0xf, true)); v += t;
    return __builtin_bit_cast(float, __builtin_amdgcn_readlane(__builtin_bit_cast(int, v), 63));
}

// ---------------------------------------------------------------------------
// Tree grid barrier (R10). R9's single counter serialized 64 same-line RMWs
// at L3 (~1.5-2us/iter arrival chain). Now: 8 padded leaf counters (blocks
// b&7; 8 serialized RMWs each, leaves in parallel) -> root (8 RMWs) -> a
// generation flag for the read-only spin. Serial RMW depth 64 -> 16.
// Ordering: leaf/root RMWs are acq_rel, gen store is release -> the last
// finisher's gen release happens-after ALL blocks' cb writes (acq_rel
// chain); spinners acquire gen -> colbuf reads ordered. Relaxed spin with
// periodic acquire (deadlock-proof), final acquire load.
// Layout in cnt[]: leaf i at cnt[i*32], root at cnt[8*32], gen at cnt[9*32].
// Counters monotonic (zeroed once by gemm block 0; max 8*512 increments).
// ---------------------------------------------------------------------------
__device__ __forceinline__ void grid_barrier(int* cnt, int g) {
    __syncthreads();
    if (threadIdx.x == 0) {
        int* leaf = cnt + ((int)blockIdx.x & 7) * LEAFSTRIDE;
        int* root = cnt + 8 * LEAFSTRIDE;
        int* gen  = cnt + 9 * LEAFSTRIDE;
        const int old = __hip_atomic_fetch_add(leaf, 1, __ATOMIC_ACQ_REL, __HIP_MEMORY_SCOPE_AGENT);
        if ((old & 7) == 7) {                 // 8th arrival of this generation
            const int r = __hip_atomic_fetch_add(root, 1, __ATOMIC_ACQ_REL, __HIP_MEMORY_SCOPE_AGENT);
            if ((r & 7) == 7)                 // last leaf of this generation
                __hip_atomic_store(gen, g + 1, __ATOMIC_RELEASE, __HIP_MEMORY_SCOPE_AGENT);
        }
        int it = 0;
        for (;;) {
            int v = __hip_atomic_load(gen, __ATOMIC_RELAXED, __HIP_MEMORY_SCOPE_AGENT);
            if (v >= g + 1) break;
            if ((++it & 7) == 0) {
                v = __hip_atomic_load(gen, __ATOMIC_ACQUIRE, __HIP_MEMORY_SCOPE_AGENT);
                if (v >= g + 1) break;
            }
            __builtin_amdgcn_s_sleep(1);
        }
        (void)__hip_atomic_load(gen, __ATOMIC_ACQUIRE, __HIP_MEMORY_SCOPE_AGENT);
    }
    __syncthreads();
}

// ---------------------------------------------------------------------------
// Kernel 2 (cooperative): sinkhorn + top-2 + softmax gather. Identical math
// to R7-R9 (bit-identical iterates); only barrier internals changed.
// Grid = 64 blocks x 1024 threads. Wave w owns tokens b*256+w*16..+15;
// lane = expert. cost in registers.
// ---------------------------------------------------------------------------
__global__ __launch_bounds__(1024) void sinkhorn_router(const float* __restrict__ L,
                                                        float* __restrict__ colbuf,
                                                        int* __restrict__ cnt,
                                                        float* __restrict__ out,
                                                        int nh) {
    __shared__ float part[16][64];
    __shared__ float redq[64][17];
    __shared__ float d1s[64];
    __shared__ float err_s;

    const int b     = blockIdx.x;   // 0..63
    const int tid   = (int)threadIdx.x;
    const int w     = tid >> 6;     // wave 0..15
    const int lane  = tid & 63;     // expert index
    const int tbase = b * 256 + w * 16;

    float logit[16], cost[16], dreg[16];
#pragma unroll
    for (int j = 0; j < 16; ++j) {
        const int t = tbase + j;
        float l = L[(size_t)t * NEXP + lane];
        for (int h = 1; h < nh; ++h)
            l += L[(size_t)h * NTOK * NEXP + (size_t)t * NEXP + lane];
        logit[j] = l;
        cost[j]  = expf(l);
        dreg[j]  = 0.0f;
    }

    float d1l   = 1.0f;   // this lane's d1[e]
    float d1old = 1.0f;   // previous d1 (used by tid<64 for err)
    int   g     = 0;

    for (;;) {
        // ---- phase A: d0 per token (DPP reduce) + per-wave column partials
        float colacc = 0.0f;
#pragma unroll
        for (int j = 0; j < 16; ++j) {
            const float s = wave_sum64(d1l * cost[j]);   // wave-uniform
            const float d0 = (1.0f / 16384.0f) / (s + EPSF);
            dreg[j] = d0;
            colacc = fmaf(d0, cost[j], colacc);
        }
        part[w][lane] = colacc;
        __syncthreads();

        float* cb = colbuf + (size_t)(g & 1) * (NEXP * SBLK);
        if (tid < 64) {
            float s = part[0][tid];
#pragma unroll
            for (int q = 1; q < 16; ++q) s += part[q][tid];
            cb[tid * SBLK + b] = s;     // reader-coalesced layout [e][b]
        }
        grid_barrier(cnt, g);

        // ---- phase B: cross-block column reduction, all 1024 threads ----
        {
            const int e = tid >> 4;     // 0..63
            const int q = tid & 15;     // 0..15 -> blocks q*4..q*4+3
            const float4 v = *(const float4*)(cb + e * SBLK + q * 4);
            redq[e][q] = (v.x + v.y) + (v.z + v.w);
        }
        __syncthreads();

        if (tid < 64) {
            float tot = redq[tid][0];
#pragma unroll
            for (int q = 1; q < 16; ++q) tot += redq[tid][q];
            const float d1n = (1.0f / 64.0f) / (tot + EPSF);
            float diff = fabsf(d1old - d1n);
#pragma unroll
            for (int m = 32; m; m >>= 1) diff += __shfl_xor(diff, m, 64);
            d1s[tid] = d1n;
            d1old    = d1n;
            if (tid == 0) err_s = diff * (1.0f / 64.0f);
        }
        __syncthreads();
        d1l = d1s[lane];
        const float err = err_s;
        ++g;
        if (!(err > TOLF) || g >= 512) break;   // matches while(err>tol); NaN stops
    }

    // ---- final: per token top-2 of d1*cost*d0, softmax gather ----
#pragma unroll 1
    for (int j = 0; j < 16; ++j) {
        const int t = tbase + j;
        const float v = (d1l * cost[j]) * dreg[j];

        float bv = v; int bi = lane;
#pragma unroll
        for (int m = 32; m; m >>= 1) {
            const float ov = __shfl_xor(bv, m, 64);
            const int   oi = __shfl_xor(bi, m, 64);
            if (ov > bv || (ov == bv && oi < bi)) { bv = ov; bi = oi; }
        }
        const int i1 = bi;

        const float v2 = (lane == i1) ? -INFINITY : v;
        float bv2 = v2; int bi2 = lane;
#pragma unroll
        for (int m = 32; m; m >>= 1) {
            const float ov = __shfl_xor(bv2, m, 64);
            const int   oi = __shfl_xor(bi2, m, 64);
            if (ov > bv2 || (ov == bv2 && oi < bi2)) { bv2 = ov; bi2 = oi; }
        }
        const int i2 = bi2;

        float mx = logit[j];
#pragma unroll
        for (int m = 32; m; m >>= 1) mx = fmaxf(mx, __shfl_xor(mx, m, 64));
        const float e = expf(logit[j] - mx);
        float se = e;
#pragma unroll
        for (int m = 32; m; m >>= 1) se += __shfl_xor(se, m, 64);

        const float p1 = __shfl(e, i1, 64) / se;
        const float p2 = __shfl(e, i2, 64) / se;

        if (lane == 0) {
            out[(size_t)t * 2 + 0] = p1;
            out[(size_t)t * 2 + 1] = p2;
            out[(size_t)NTOK * 2 + (size_t)t * 2 + 0] = (float)i1;
            out[(size_t)NTOK * 2 + (size_t)t * 2 + 1] = (float)i2;
        }
    }
}

// ---------------------------------------------------------------------------
// ws layout (4.25 MB total):
//   [0,      4.0MB)  L  f32 [16384][64]
//   [4.0MB, +32KB )  colbuf (2 x 64 x 64 f32, sinkhorn ping-pong)
//   [+1.25KB)        tree-barrier area: 8 leaves + root + gen, 128B-padded
//                    (zeroed by gemm block 0 each launch)
// ---------------------------------------------------------------------------
extern "C" void kernel_launch(void* const* d_in, const int* in_sizes, int n_in,
                              void* d_out, int out_size, void* d_ws, size_t ws_size,
                              hipStream_t stream) {
    const float* x = (const float*)d_in[0];
    const float* W = (const float*)d_in[1];
    float* out = (float*)d_out;

    float* L      = (float*)d_ws;
    float* colbuf = L + (size_t)NTOK * NEXP;
    int*   cnt    = (int*)(colbuf + 2 * NEXP * SBLK);

    gemm_mfma<<<dim3(256), dim3(1024), 0, stream>>>(x, W, L, cnt);

    int nh = 1;
    void* args[] = { (void*)&L, (void*)&colbuf, (void*)&cnt, (void*)&out, (void*)&nh };
    hipLaunchCooperativeKernel((void*)sinkhorn_router, dim3(SBLK), dim3(1024),
                               args, 0, stream);
}

// Round 13
// 252.119 us; speedup vs baseline: 1.2842x; 1.0777x over previous
//
#include <hip/hip_runtime.h>
#include <math.h>

#define HID   2048
#define NEXP  64
#define NTOK  16384
#define SBLK  64      // sinkhorn blocks
#define TOLF  1e-4f
#define EPSF  1e-8f

typedef _Float16 f16x8 __attribute__((ext_vector_type(8)));
typedef float    f32x4 __attribute__((ext_vector_type(4)));

// ---------------------------------------------------------------------------
// f16x3 split of 8 fp32 values: h = RTN f32->f16, l = (v - h) * 2048 (exact
// residual, Sterbenz). Identical math every round -> bitwise-identical L.
// ---------------------------------------------------------------------------
__device__ __forceinline__ void cvt8(const float4 a, const float4 b,
                                     f16x8& h, f16x8& l) {
    const float v[8] = {a.x, a.y, a.z, a.w, b.x, b.y, b.z, b.w};
#pragma unroll
    for (int j = 0; j < 8; ++j) {
        const _Float16 hh = (_Float16)v[j];
        h[j] = hh;
        l[j] = (_Float16)((v[j] - (float)hh) * 2048.0f);
    }
}

// ---------------------------------------------------------------------------
// Kernel 1: f16x3 MFMA logits, double-buffered LDS B, tail-issue schedule
// (R10 structure, unchanged this round). Grid = 256 x 1024 thr (16 waves =
// 4 token-groups x 4 k-slices). Also zeroes the sinkhorn tree-barrier area.
// ---------------------------------------------------------------------------
#define BSTRIDE 40               // f16 per LDS B row (32 data + 8 pad)
#define BUFELTS (8 * 64 * BSTRIDE)   // 4 wk x 2(h/l) x 64 rows x 40 = 20480 f16
#define LEAFSTRIDE 32            // ints (128 B) between barrier counters

__global__ __launch_bounds__(1024, 4) void gemm_mfma(const float* __restrict__ x,
                                                     const float* __restrict__ W,
                                                     float* __restrict__ L,
                                                     int* __restrict__ cnt) {
    // 80 KB static LDS: two 40960 B B-buffers during the loop,
    // red[16][1024] f32 (64 KB) in the epilogue (aliased after final barrier).
    __shared__ __align__(16) char smem[81920];
    _Float16* Bs0 = (_Float16*)smem;
    _Float16* Bs1 = Bs0 + BUFELTS;
    float*    red = (float*)smem;

    const int tid = (int)threadIdx.x;
    if (blockIdx.x == 0 && tid < 10 * LEAFSTRIDE) cnt[tid] = 0;  // barrier area

    const int waveid = tid >> 6;       // 0..15
    const int wt     = waveid >> 2;    // token group 0..3 (16 tokens each)
    const int wk     = waveid & 3;     // k-slice 0..3 (512 k each)
    const int lane   = tid & 63;
    const int lo     = lane & 15;      // token row (A) / expert col (D)
    const int hi     = lane >> 4;      // k-block 0..3
    const int t0     = (int)blockIdx.x * 64;
    const int kb     = wk * 512;

    // staging: group-local thread gt owns row srow, frag sfrag (8 fp32 in,
    // 8+8 f16 out to the h-row and l-row).
    const int gt    = wt * 64 + lane;
    const int srow  = gt >> 2;         // 0..63
    const int sfrag = gt & 3;          // 0..3 -> floats sfrag*8..+7
    const float* sgp = W + (size_t)srow * HID + kb + sfrag * 8;
    const int swh = ((wk * 2 + 0) * 64 + srow) * BSTRIDE + sfrag * 8;
    const int swl = ((wk * 2 + 1) * 64 + srow) * BSTRIDE + sfrag * 8;

    const float* xp = x + (size_t)(t0 + wt * 16 + lo) * HID + kb + hi * 8;

    f32x4 acc_hh[4], acc_hl[4];
#pragma unroll
    for (int n = 0; n < 4; ++n) {
        acc_hh[n] = f32x4{0.f, 0.f, 0.f, 0.f};
        acc_hl[n] = f32x4{0.f, 0.f, 0.f, 0.f};
    }

    // ---- prologue: chunks 0,1 staged; A chunk0 (cur) + chunk1 (nxt);
    //      staging regs primed with chunk 2 BEFORE the first barrier (the
    //      one-time drain there is acceptable).
    float4 sv0 = *(const float4*)(sgp);
    float4 sv1 = *(const float4*)(sgp + 4);
    {
        const float4 t2 = *(const float4*)(sgp + 32);
        const float4 t3 = *(const float4*)(sgp + 36);
        f16x8 h, l;
        cvt8(sv0, sv1, h, l);
        *(f16x8*)&Bs0[swh] = h;
        *(f16x8*)&Bs0[swl] = l;
        cvt8(t2, t3, h, l);
        *(f16x8*)&Bs1[swh] = h;
        *(f16x8*)&Bs1[swl] = l;
    }
    float4 a0c = *(const float4*)(xp);
    float4 a1c = *(const float4*)(xp + 4);
    float4 a0n = *(const float4*)(xp + 32);
    float4 a1n = *(const float4*)(xp + 36);
    sv0 = *(const float4*)(sgp + 64);   // chunk 2 staging (written tail c=0)
    sv1 = *(const float4*)(sgp + 68);
    __syncthreads();

#pragma unroll 2
    for (int c = 0; c < 16; ++c) {
        // ---- compute phase: NO global issues here ----
        const _Float16* Bc = (c & 1) ? Bs1 : Bs0;
        f16x8 bh[4], bl[4];
#pragma unroll
        for (int n = 0; n < 4; ++n) {
            bh[n] = *(const f16x8*)&Bc[((wk * 2 + 0) * 64 + lo + n * 16) * BSTRIDE + hi * 8];
            bl[n] = *(const f16x8*)&Bc[((wk * 2 + 1) * 64 + lo + n * 16) * BSTRIDE + hi * 8];
        }

        f16x8 ah, al;
        const float av[8] = {a0c.x, a0c.y, a0c.z, a0c.w, a1c.x, a1c.y, a1c.z, a1c.w};
#pragma unroll
        for (int j = 0; j < 8; ++j) {
            const _Float16 hh = (_Float16)av[j];
            ah[j] = hh;
            al[j] = (_Float16)((av[j] - (float)hh) * 2048.0f);
        }

#pragma unroll
        for (int n = 0; n < 4; ++n)
            acc_hh[n] = __builtin_amdgcn_mfma_f32_16x16x32_f16(ah, bh[n], acc_hh[n], 0, 0, 0);
#pragma unroll
        for (int n = 0; n < 4; ++n)
            acc_hl[n] = __builtin_amdgcn_mfma_f32_16x16x32_f16(ah, bl[n], acc_hl[n], 0, 0, 0);
#pragma unroll
        for (int n = 0; n < 4; ++n)
            acc_hl[n] = __builtin_amdgcn_mfma_f32_16x16x32_f16(al, bh[n], acc_hl[n], 0, 0, 0);

        __syncthreads();   // drains only loads issued in tail(c-1): >=1 phase old

        // ---- tail: writes + ALL global issues for the next chunks ----
        if (c + 2 < 16) {              // write chunk c+2 (sv issued tail(c-1))
            _Float16* Bw = (c & 1) ? Bs1 : Bs0;
            f16x8 h, l;
            cvt8(sv0, sv1, h, l);
            *(f16x8*)&Bw[swh] = h;
            *(f16x8*)&Bw[swl] = l;
        }
        a0c = a0n; a1c = a1n;          // A chunk c+1 (issued tail(c-1))
        if (c + 2 < 16) {              // issue A chunk c+2
            a0n = *(const float4*)(xp + (c + 2) * 32);
            a1n = *(const float4*)(xp + (c + 2) * 32 + 4);
        }
        if (c + 3 < 16) {              // issue W chunk c+3 (written tail(c+1))
            sv0 = *(const float4*)(sgp + (c + 3) * 32);
            sv1 = *(const float4*)(sgp + (c + 3) * 32 + 4);
        }
    }

    // epilogue: per-wave partials -> red (aliases B buffers; barriered)
#pragma unroll
    for (int n = 0; n < 4; ++n)
#pragma unroll
        for (int r = 0; r < 4; ++r)
            red[waveid * 1024 + n * 256 + r * 64 + lane] =
                acc_hh[n][r] + acc_hl[n][r] * (1.0f / 2048.0f);
    __syncthreads();

    // cross-wk reduce + coalesced write (unchanged mapping)
    {
        const int o      = tid * 4;
        const int t_loc  = o >> 6;
        const int e      = o & 63;
        const int wt_src = t_loc >> 4;
        const int tl     = t_loc & 15;
        const int idx    = (e >> 4) * 256 + (tl & 3) * 64 + (tl >> 2) * 16 + (e & 15);
        float4 s = *(const float4*)&red[(wt_src * 4 + 0) * 1024 + idx];
#pragma unroll
        for (int q = 1; q < 4; ++q) {
            const float4 v = *(const float4*)&red[(wt_src * 4 + q) * 1024 + idx];
            s.x += v.x; s.y += v.y; s.z += v.z; s.w += v.w;
        }
        *(float4*)(L + (size_t)(t0 + t_loc) * NEXP + e) = s;
    }
}

// ---------------------------------------------------------------------------
// wave-wide f32 sum via DPP (VALU-only). row_shr 1/2/4/8 within 16-lane rows,
// row_bcast15/31 merge rows; lane 63 holds total; readlane -> wave-uniform.
// ---------------------------------------------------------------------------
__device__ __forceinline__ float wave_sum64(float v) {
    int x;
    float t;
    x = __builtin_bit_cast(int, v);
    t = __builtin_bit_cast(float, __builtin_amdgcn_update_dpp(0, x, 0x111, 0xf, 0xf, true)); v += t;
    x = __builtin_bit_cast(int, v);
    t = __builtin_bit_cast(float, __builtin_amdgcn_update_dpp(0, x, 0x112, 0xf, 0xf, true)); v += t;
    x = __builtin_bit_cast(int, v);
    t = __builtin_bit_cast(float, __builtin_amdgcn_update_dpp(0, x, 0x114, 0xf, 0xf, true)); v += t;
    x = __builtin_bit_cast(int, v);
    t = __builtin_bit_cast(float, __builtin_amdgcn_update_dpp(0, x, 0x118, 0xf, 0xf, true)); v += t;
    x = __builtin_bit_cast(int, v);
    t = __builtin_bit_cast(float, __builtin_amdgcn_update_dpp(0, x, 0x142, 0xa, 0xf, true)); v += t;
    x = __builtin_bit_cast(int, v);
    t = __builtin_bit_cast(float, __builtin_amdgcn_update_dpp(0, x, 0x143, 0xc, 0xf, true)); v += t;
    return __builtin_bit_cast(float, __builtin_amdgcn_readlane(__builtin_bit_cast(int, v), 63));
}

// ---------------------------------------------------------------------------
// Tree grid barrier (R10 structure, unchanged). 8 padded leaf counters ->
// root -> generation flag; relaxed spin with periodic acquire. Counters
// monotonic, zeroed by gemm block 0 (dispatch boundary = release).
// The consuming kernel is a PLAIN launch -- since R7 nothing in
// sinkhorn_router uses cooperative semantics; co-residency of 64 blocks
// (~8.5 KB LDS, 16 waves) on a 256-CU exclusive chip is guaranteed by
// capacity (the same resource set was co-resident as a cooperative grid
// for 5 rounds). Failure mode if that ever broke = visible hang, not
// silent corruption.
// ---------------------------------------------------------------------------
__device__ __forceinline__ void grid_barrier(int* cnt, int g) {
    __syncthreads();
    if (threadIdx.x == 0) {
        int* leaf = cnt + ((int)blockIdx.x & 7) * LEAFSTRIDE;
        int* root = cnt + 8 * LEAFSTRIDE;
        int* gen  = cnt + 9 * LEAFSTRIDE;
        const int old = __hip_atomic_fetch_add(leaf, 1, __ATOMIC_ACQ_REL, __HIP_MEMORY_SCOPE_AGENT);
        if ((old & 7) == 7) {                 // 8th arrival of this generation
            const int r = __hip_atomic_fetch_add(root, 1, __ATOMIC_ACQ_REL, __HIP_MEMORY_SCOPE_AGENT);
            if ((r & 7) == 7)                 // last leaf of this generation
                __hip_atomic_store(gen, g + 1, __ATOMIC_RELEASE, __HIP_MEMORY_SCOPE_AGENT);
        }
        int it = 0;
        for (;;) {
            int v = __hip_atomic_load(gen, __ATOMIC_RELAXED, __HIP_MEMORY_SCOPE_AGENT);
            if (v >= g + 1) break;
            if ((++it & 7) == 0) {
                v = __hip_atomic_load(gen, __ATOMIC_ACQUIRE, __HIP_MEMORY_SCOPE_AGENT);
                if (v >= g + 1) break;
            }
            __builtin_amdgcn_s_sleep(1);
        }
        (void)__hip_atomic_load(gen, __ATOMIC_ACQUIRE, __HIP_MEMORY_SCOPE_AGENT);
    }
    __syncthreads();
}

// ---------------------------------------------------------------------------
// Kernel 2: sinkhorn + top-2 + softmax gather. Identical math to R7-R11
// (bit-identical iterates). Launched as a PLAIN kernel, not
// hipLaunchCooperativeKernel (launch-overhead probe; no code change here).
// Grid = 64 blocks x 1024 threads. Wave w owns tokens b*256+w*16..+15;
// lane = expert. cost in registers.
// ---------------------------------------------------------------------------
__global__ __launch_bounds__(1024) void sinkhorn_router(const float* __restrict__ L,
                                                        float* __restrict__ colbuf,
                                                        int* __restrict__ cnt,
                                                        float* __restrict__ out,
                                                        int nh) {
    __shared__ float part[16][64];
    __shared__ float redq[64][17];
    __shared__ float d1s[64];
    __shared__ float err_s;

    const int b     = blockIdx.x;   // 0..63
    const int tid   = (int)threadIdx.x;
    const int w     = tid >> 6;     // wave 0..15
    const int lane  = tid & 63;     // expert index
    const int tbase = b * 256 + w * 16;

    float logit[16], cost[16], dreg[16];
#pragma unroll
    for (int j = 0; j < 16; ++j) {
        const int t = tbase + j;
        float l = L[(size_t)t * NEXP + lane];
        for (int h = 1; h < nh; ++h)
            l += L[(size_t)h * NTOK * NEXP + (size_t)t * NEXP + lane];
        logit[j] = l;
        cost[j]  = expf(l);
        dreg[j]  = 0.0f;
    }

    float d1l   = 1.0f;   // this lane's d1[e]
    float d1old = 1.0f;   // previous d1 (used by tid<64 for err)
    int   g     = 0;

    for (;;) {
        // ---- phase A: d0 per token (DPP reduce) + per-wave column partials
        float colacc = 0.0f;
#pragma unroll
        for (int j = 0; j < 16; ++j) {
            const float s = wave_sum64(d1l * cost[j]);   // wave-uniform
            const float d0 = (1.0f / 16384.0f) / (s + EPSF);
            dreg[j] = d0;
            colacc = fmaf(d0, cost[j], colacc);
        }
        part[w][lane] = colacc;
        __syncthreads();

        float* cb = colbuf + (size_t)(g & 1) * (NEXP * SBLK);
        if (tid < 64) {
            float s = part[0][tid];
#pragma unroll
            for (int q = 1; q < 16; ++q) s += part[q][tid];
            cb[tid * SBLK + b] = s;     // reader-coalesced layout [e][b]
        }
        grid_barrier(cnt, g);

        // ---- phase B: cross-block column reduction, all 1024 threads ----
        {
            const int e = tid >> 4;     // 0..63
            const int q = tid & 15;     // 0..15 -> blocks q*4..q*4+3
            const float4 v = *(const float4*)(cb + e * SBLK + q * 4);
            redq[e][q] = (v.x + v.y) + (v.z + v.w);
        }
        __syncthreads();

        if (tid < 64) {
            float tot = redq[tid][0];
#pragma unroll
            for (int q = 1; q < 16; ++q) tot += redq[tid][q];
            const float d1n = (1.0f / 64.0f) / (tot + EPSF);
            float diff = fabsf(d1old - d1n);
#pragma unroll
            for (int m = 32; m; m >>= 1) diff += __shfl_xor(diff, m, 64);
            d1s[tid] = d1n;
            d1old    = d1n;
            if (tid == 0) err_s = diff * (1.0f / 64.0f);
        }
        __syncthreads();
        d1l = d1s[lane];
        const float err = err_s;
        ++g;
        if (!(err > TOLF) || g >= 512) break;   // matches while(err>tol); NaN stops
    }

    // ---- final: per token top-2 of d1*cost*d0, softmax gather ----
#pragma unroll 1
    for (int j = 0; j < 16; ++j) {
        const int t = tbase + j;
        const float v = (d1l * cost[j]) * dreg[j];

        float bv = v; int bi = lane;
#pragma unroll
        for (int m = 32; m; m >>= 1) {
            const float ov = __shfl_xor(bv, m, 64);
            const int   oi = __shfl_xor(bi, m, 64);
            if (ov > bv || (ov == bv && oi < bi)) { bv = ov; bi = oi; }
        }
        const int i1 = bi;

        const float v2 = (lane == i1) ? -INFINITY : v;
        float bv2 = v2; int bi2 = lane;
#pragma unroll
        for (int m = 32; m; m >>= 1) {
            const float ov = __shfl_xor(bv2, m, 64);
            const int   oi = __shfl_xor(bi2, m, 64);
            if (ov > bv2 || (ov == bv2 && oi < bi2)) { bv2 = ov; bi2 = oi; }
        }
        const int i2 = bi2;

        float mx = logit[j];
#pragma unroll
        for (int m = 32; m; m >>= 1) mx = fmaxf(mx, __shfl_xor(mx, m, 64));
        const float e = expf(logit[j] - mx);
        float se = e;
#pragma unroll
        for (int m = 32; m; m >>= 1) se += __shfl_xor(se, m, 64);

        const float p1 = __shfl(e, i1, 64) / se;
        const float p2 = __shfl(e, i2, 64) / se;

        if (lane == 0) {
            out[(size_t)t * 2 + 0] = p1;
            out[(size_t)t * 2 + 1] = p2;
            out[(size_t)NTOK * 2 + (size_t)t * 2 + 0] = (float)i1;
            out[(size_t)NTOK * 2 + (size_t)t * 2 + 1] = (float)i2;
        }
    }
}

// ---------------------------------------------------------------------------
// ws layout (4.25 MB total):
//   [0,      4.0MB)  L  f32 [16384][64]
//   [4.0MB, +32KB )  colbuf (2 x 64 x 64 f32, sinkhorn ping-pong)
//   [+1.25KB)        tree-barrier area: 8 leaves + root + gen, 128B-padded
//                    (zeroed by gemm block 0 each launch)
// ---------------------------------------------------------------------------
extern "C" void kernel_launch(void* const* d_in, const int* in_sizes, int n_in,
                              void* d_out, int out_size, void* d_ws, size_t ws_size,
                              hipStream_t stream) {
    const float* x = (const float*)d_in[0];
    const float* W = (const float*)d_in[1];
    float* out = (float*)d_out;

    float* L      = (float*)d_ws;
    float* colbuf = L + (size_t)NTOK * NEXP;
    int*   cnt    = (int*)(colbuf + 2 * NEXP * SBLK);

    gemm_mfma<<<dim3(256), dim3(1024), 0, stream>>>(x, W, L, cnt);

    // Plain launch (was hipLaunchCooperativeKernel). Nothing in the kernel
    // uses cooperative semantics since R7's custom barrier; 64 blocks
    // trivially co-resident on 256 CUs (capacity argument, G16-with-care).
    sinkhorn_router<<<dim3(SBLK), dim3(1024), 0, stream>>>(L, colbuf, cnt, out, 1);
}